// Round 1
// baseline (4597.681 us; speedup 1.0000x reference)
//
#include <hip/hip_runtime.h>
#include <math.h>

#define SEQ    4096
#define DIM    1024
#define NEXP   8
#define NSLOT  512
#define ES     4096    // NEXP*NSLOT
#define HIDDEN 4096
#define NB     2
#define RMS_SCALE 32.0f   // sqrt(DIM)

__device__ __forceinline__ float gelu_exact(float x) {
    return 0.5f * x * (1.0f + erff(x * 0.70710678118654752f));
}

// ---------------- RMSNorm: one block (256 thr) per 1024-dim row ----------------
__global__ void rmsnorm_kernel(const float* __restrict__ in,
                               const float* __restrict__ gamma,
                               float* __restrict__ out) {
    int row = blockIdx.x;
    int t = threadIdx.x;
    float4 v = reinterpret_cast<const float4*>(in + (size_t)row * DIM)[t];
    float ss = v.x*v.x + v.y*v.y + v.z*v.z + v.w*v.w;
    #pragma unroll
    for (int off = 32; off >= 1; off >>= 1) ss += __shfl_down(ss, off, 64);
    __shared__ float red[4];
    if ((t & 63) == 0) red[t >> 6] = ss;
    __syncthreads();
    float tot = red[0] + red[1] + red[2] + red[3];
    float inv = RMS_SCALE / fmaxf(sqrtf(tot), 1e-12f);
    float4 g = reinterpret_cast<const float4*>(gamma)[t];
    float4 o;
    o.x = v.x * inv * g.x;
    o.y = v.y * inv * g.y;
    o.z = v.z * inv * g.z;
    o.w = v.w * inv * g.w;
    reinterpret_cast<float4*>(out + (size_t)row * DIM)[t] = o;
}

// ---------- column softmax stats (softmax over tokens n, per (b, es) column) ----------
// grid (ES/256, 8 chunks, NB); each thread owns one column over 512 rows
__global__ void col_stats_partial(const float* __restrict__ logits,
                                  float* __restrict__ pmax, float* __restrict__ psum) {
    int col = blockIdx.x * 256 + threadIdx.x;
    int ch  = blockIdx.y;
    int b   = blockIdx.z;
    const float* base = logits + ((size_t)b * SEQ + (size_t)ch * 512) * ES + col;
    float m = -INFINITY, s = 0.f;
    for (int n = 0; n < 512; ++n) {
        float v = base[(size_t)n * ES];
        float mn = fmaxf(m, v);
        s = s * __expf(m - mn) + __expf(v - mn);
        m = mn;
    }
    size_t idx = ((size_t)b * 8 + ch) * ES + col;
    pmax[idx] = m; psum[idx] = s;
}

__global__ void col_stats_reduce(const float* __restrict__ pmax, const float* __restrict__ psum,
                                 float* __restrict__ cmax, float* __restrict__ cinv) {
    int col = blockIdx.x * 256 + threadIdx.x;
    int b   = blockIdx.y;
    float m = -INFINITY, s = 0.f;
    for (int ch = 0; ch < 8; ++ch) {
        size_t idx = ((size_t)b * 8 + ch) * ES + col;
        float m2 = pmax[idx], s2 = psum[idx];
        float mn = fmaxf(m, m2);
        s = s * __expf(m - mn) + s2 * __expf(m2 - mn);
        m = mn;
    }
    cmax[(size_t)b * ES + col] = m;
    cinv[(size_t)b * ES + col] = 1.0f / s;
}

// ---------- row softmax stats (softmax over e*s per (b,n) row) ----------
__global__ void row_stats(const float* __restrict__ logits,
                          float* __restrict__ rmax, float* __restrict__ rinv) {
    int row = blockIdx.x;                 // b*SEQ + n
    int t = threadIdx.x;
    const float* base = logits + (size_t)row * ES;
    float m = -INFINITY, s = 0.f;
    for (int i = t; i < ES; i += 256) {
        float v = base[i];
        float mn = fmaxf(m, v);
        s = s * __expf(m - mn) + __expf(v - mn);
        m = mn;
    }
    __shared__ float sm[256], ssum[256];
    sm[t] = m; ssum[t] = s;
    __syncthreads();
    for (int off = 128; off >= 1; off >>= 1) {
        if (t < off) {
            float m1 = sm[t], m2 = sm[t+off], s1 = ssum[t], s2 = ssum[t+off];
            float mn = fmaxf(m1, m2);
            sm[t] = mn;
            ssum[t] = s1 * __expf(m1 - mn) + s2 * __expf(m2 - mn);
        }
        __syncthreads();
    }
    if (t == 0) { rmax[row] = sm[0]; rinv[row] = 1.0f / ssum[0]; }
}

// ---------------- generic tiled fp32 GEMM ----------------
// C[M,N] (+epilogue) = transA(A) @ transB(B), 64x64 tile, BK=16, 256 thr, 4x4/thread
// AMODE 0: A[m][k] row-major (lda=K)
// AMODE 1: A stored as W[k][m] (row len = M); a = exp(W - tmax[m]) * tinv[m]  (col-softmax weights)
// AMODE 2: A[m][k] row-major; a = exp(A - tmax[m]) * tinv[m]                  (row-softmax weights)
// BMODE 0: B[k][n] (ldb=N)    BMODE 1: B[n][k] (ldb=K)
// EPI 0: none  1: +bias  2: +bias then exact GELU
template<int AMODE, int BMODE, int EPI>
__global__ void gemm_kernel(const float* __restrict__ A, const float* __restrict__ Bm,
                            float* __restrict__ C,
                            const float* __restrict__ tmax, const float* __restrict__ tinv,
                            const float* __restrict__ bias,
                            int M, int N, int K,
                            long aStride, long bStride, long cStride, int bMod) {
    __shared__ float As[16][64];
    __shared__ float Bs[16][64];

    int z  = blockIdx.z;
    int zb = z % bMod;
    const float* Ab = A  + (size_t)z  * aStride;
    const float* Bb = Bm + (size_t)zb * bStride;
    float*       Cb = C  + (size_t)z  * cStride;
    const float* tmz = (AMODE != 0) ? tmax + (size_t)z * M : nullptr;
    const float* tiz = (AMODE != 0) ? tinv + (size_t)z * M : nullptr;
    const float* biz = (EPI  != 0) ? bias + (size_t)zb * N : nullptr;

    int m0 = blockIdx.y * 64;
    int n0 = blockIdx.x * 64;
    int t  = threadIdx.x;
    int tx = t & 15, ty = t >> 4;

    float acc[4][4] = {};

    for (int k0 = 0; k0 < K; k0 += 16) {
        // ---- A tile -> As[k][m] ----
        if (AMODE == 0 || AMODE == 2) {
            int lm = t >> 2;
            int lk = (t & 3) * 4;
            float4 v = *reinterpret_cast<const float4*>(Ab + (size_t)(m0 + lm) * K + k0 + lk);
            if (AMODE == 2) {
                float mx = tmz[m0 + lm], sc = tiz[m0 + lm];
                v.x = __expf(v.x - mx) * sc;
                v.y = __expf(v.y - mx) * sc;
                v.z = __expf(v.z - mx) * sc;
                v.w = __expf(v.w - mx) * sc;
            }
            As[lk+0][lm] = v.x; As[lk+1][lm] = v.y; As[lk+2][lm] = v.z; As[lk+3][lm] = v.w;
        } else { // AMODE 1: W[k][m], row length M
            int lk = t >> 4;
            int lm = (t & 15) * 4;
            float4 v = *reinterpret_cast<const float4*>(Ab + (size_t)(k0 + lk) * M + m0 + lm);
            v.x = __expf(v.x - tmz[m0+lm+0]) * tiz[m0+lm+0];
            v.y = __expf(v.y - tmz[m0+lm+1]) * tiz[m0+lm+1];
            v.z = __expf(v.z - tmz[m0+lm+2]) * tiz[m0+lm+2];
            v.w = __expf(v.w - tmz[m0+lm+3]) * tiz[m0+lm+3];
            *reinterpret_cast<float4*>(&As[lk][lm]) = v;
        }
        // ---- B tile -> Bs[k][n] ----
        if (BMODE == 0) {
            int lk = t >> 4;
            int ln = (t & 15) * 4;
            float4 v = *reinterpret_cast<const float4*>(Bb + (size_t)(k0 + lk) * N + n0 + ln);
            *reinterpret_cast<float4*>(&Bs[lk][ln]) = v;
        } else {
            int ln = t >> 2;
            int lk = (t & 3) * 4;
            float4 v = *reinterpret_cast<const float4*>(Bb + (size_t)(n0 + ln) * K + k0 + lk);
            Bs[lk+0][ln] = v.x; Bs[lk+1][ln] = v.y; Bs[lk+2][ln] = v.z; Bs[lk+3][ln] = v.w;
        }
        __syncthreads();

        #pragma unroll
        for (int k = 0; k < 16; ++k) {
            float4 a = *reinterpret_cast<const float4*>(&As[k][ty*4]);
            float4 b = *reinterpret_cast<const float4*>(&Bs[k][tx*4]);
            float ar[4] = {a.x, a.y, a.z, a.w};
            float br[4] = {b.x, b.y, b.z, b.w};
            #pragma unroll
            for (int i = 0; i < 4; ++i)
                #pragma unroll
                for (int j = 0; j < 4; ++j)
                    acc[i][j] = fmaf(ar[i], br[j], acc[i][j]);
        }
        __syncthreads();
    }

    #pragma unroll
    for (int i = 0; i < 4; ++i) {
        int mrow = m0 + ty * 4 + i;
        float4 v = {acc[i][0], acc[i][1], acc[i][2], acc[i][3]};
        if (EPI >= 1) {
            v.x += biz[n0 + tx*4 + 0];
            v.y += biz[n0 + tx*4 + 1];
            v.z += biz[n0 + tx*4 + 2];
            v.w += biz[n0 + tx*4 + 3];
        }
        if (EPI == 2) {
            v.x = gelu_exact(v.x); v.y = gelu_exact(v.y);
            v.z = gelu_exact(v.z); v.w = gelu_exact(v.w);
        }
        *reinterpret_cast<float4*>(Cb + (size_t)mrow * N + n0 + tx*4) = v;
    }
}

extern "C" void kernel_launch(void* const* d_in, const int* in_sizes, int n_in,
                              void* d_out, int out_size, void* d_ws, size_t ws_size,
                              hipStream_t stream) {
    const float* x    = (const float*)d_in[0];
    const float* ng   = (const float*)d_in[1];
    const float* sg   = (const float*)d_in[2];
    const float* semb = (const float*)d_in[3];
    const float* w1   = (const float*)d_in[4];
    const float* b1   = (const float*)d_in[5];
    const float* w2   = (const float*)d_in[6];
    const float* b2   = (const float*)d_in[7];
    float* out = (float*)d_out;

    // workspace layout (floats) — total ~96.7M floats = 387 MB
    float* ws     = (float*)d_ws;
    float* xn     = ws;                  // 8192*1024
    float* sn     = xn     + 8388608;    // 4096*1024
    float* logits = sn     + 4194304;    // 2*4096*4096
    float* slots  = logits + 33554432;   // 2*4096*1024
    float* hbuf   = slots  + 8388608;    // 16*512*4096
    float* eo     = hbuf   + 33554432;   // 16*512*1024
    float* pmax   = eo     + 8388608;    // 2*8*4096
    float* psum   = pmax   + 65536;
    float* cmax   = psum   + 65536;      // 2*4096
    float* cinv   = cmax   + 8192;
    float* rmax   = cinv   + 8192;
    float* rinv   = rmax   + 8192;

    // 1. RMSNorms
    rmsnorm_kernel<<<NB*SEQ, 256, 0, stream>>>(x, ng, xn);
    rmsnorm_kernel<<<NEXP*NSLOT, 256, 0, stream>>>(semb, sg, sn);

    // 2. logits = xn @ sn^T   [8192 x 4096], K=1024
    gemm_kernel<0,1,0><<<dim3(ES/64, (NB*SEQ)/64, 1), 256, 0, stream>>>(
        xn, sn, logits, nullptr, nullptr, nullptr,
        NB*SEQ, ES, DIM, 0L, 0L, 0L, 1<<30);

    // 3. softmax stats
    col_stats_partial<<<dim3(ES/256, 8, NB), 256, 0, stream>>>(logits, pmax, psum);
    col_stats_reduce<<<dim3(ES/256, NB), 256, 0, stream>>>(pmax, psum, cmax, cinv);
    row_stats<<<NB*SEQ, 256, 0, stream>>>(logits, rmax, rinv);

    // 4. slots[es,d] = sum_n dispatch[n,es] * xn[n,d]   (per batch)  M=ES,N=DIM,K=SEQ
    gemm_kernel<1,0,0><<<dim3(DIM/64, ES/64, NB), 256, 0, stream>>>(
        logits, xn, slots, cmax, cinv, nullptr,
        ES, DIM, SEQ, (long)SEQ*ES, (long)SEQ*DIM, (long)ES*DIM, 1<<30);

    // 5. FF1: h = gelu(slots @ w1 + b1)   z = b*8+e, M=512,N=HID,K=DIM
    gemm_kernel<0,0,2><<<dim3(HIDDEN/64, NSLOT/64, NB*NEXP), 256, 0, stream>>>(
        slots, w1, hbuf, nullptr, nullptr, b1,
        NSLOT, HIDDEN, DIM, (long)NSLOT*DIM, (long)DIM*HIDDEN, (long)NSLOT*HIDDEN, NEXP);

    // 6. FF2: eo = h @ w2 + b2   M=512,N=DIM,K=HID
    gemm_kernel<0,0,1><<<dim3(DIM/64, NSLOT/64, NB*NEXP), 256, 0, stream>>>(
        hbuf, w2, eo, nullptr, nullptr, b2,
        NSLOT, DIM, HIDDEN, (long)NSLOT*HIDDEN, (long)HIDDEN*DIM, (long)NSLOT*DIM, NEXP);

    // 7. out[n,d] = sum_m combine[n,m] * eo[m,d]   (per batch)  M=SEQ,N=DIM,K=ES
    gemm_kernel<2,0,0><<<dim3(DIM/64, SEQ/64, NB), 256, 0, stream>>>(
        logits, eo, out, rmax, rinv, nullptr,
        SEQ, DIM, ES, (long)SEQ*ES, (long)ES*DIM, (long)SEQ*DIM, 1<<30);
}

// Round 2
// 865.415 us; speedup vs baseline: 5.3127x; 5.3127x over previous
//
#include <hip/hip_runtime.h>
#include <math.h>

#define SEQ    4096
#define DIM    1024
#define NEXP   8
#define NSLOT  512
#define ES     4096
#define HID    4096
#define NB     2
#define RMS_SCALE 32.0f

typedef __attribute__((ext_vector_type(4))) float f32x4;
typedef __attribute__((ext_vector_type(8))) short bf16x8;
typedef __attribute__((ext_vector_type(4))) unsigned short us4;

__device__ __forceinline__ unsigned short f2bf(float f) {
    unsigned u = __float_as_uint(f);
    u += 0x7fff + ((u >> 16) & 1);          // round-to-nearest-even
    return (unsigned short)(u >> 16);
}
__device__ __forceinline__ float bf2f(unsigned short h) {
    return __uint_as_float(((unsigned)h) << 16);
}
__device__ __forceinline__ float gelu_exact(float x) {
    return 0.5f * x * (1.0f + erff(x * 0.70710678118654752f));
}

#define GLOAD_LDS16(gp, lp) \
    __builtin_amdgcn_global_load_lds((const __attribute__((address_space(1))) void*)(gp), \
                                     (__attribute__((address_space(3))) void*)(lp), 16, 0, 0)

// ---------------- RMSNorm + bf16 hi/lo split into K-concat layout ----------------
// ORDER 0: [hi | hi | lo]  (for x -> A_cat)    ORDER 1: [hi | lo | hi]  (for sn -> B_cat)
template<int ORDER>
__global__ void rmsnorm_split(const float* __restrict__ in, const float* __restrict__ gamma,
                              unsigned short* __restrict__ outc) {
    int row = blockIdx.x;
    int t = threadIdx.x;
    float4 v = reinterpret_cast<const float4*>(in + (size_t)row * DIM)[t];
    float ss = v.x*v.x + v.y*v.y + v.z*v.z + v.w*v.w;
    #pragma unroll
    for (int off = 32; off >= 1; off >>= 1) ss += __shfl_down(ss, off, 64);
    __shared__ float red[4];
    if ((t & 63) == 0) red[t >> 6] = ss;
    __syncthreads();
    float inv = RMS_SCALE / fmaxf(sqrtf(red[0] + red[1] + red[2] + red[3]), 1e-12f);
    float4 g = reinterpret_cast<const float4*>(gamma)[t];
    float f[4] = {v.x*inv*g.x, v.y*inv*g.y, v.z*inv*g.z, v.w*inv*g.w};
    us4 hv, lv;
    #pragma unroll
    for (int q = 0; q < 4; ++q) {
        unsigned short h = f2bf(f[q]);
        hv[q] = h;
        lv[q] = f2bf(f[q] - bf2f(h));
    }
    unsigned short* rb = outc + (size_t)row * 3072;
    *reinterpret_cast<us4*>(&rb[t*4]) = hv;
    if (ORDER == 0) {
        *reinterpret_cast<us4*>(&rb[1024 + t*4]) = hv;
        *reinterpret_cast<us4*>(&rb[2048 + t*4]) = lv;
    } else {
        *reinterpret_cast<us4*>(&rb[1024 + t*4]) = lv;
        *reinterpret_cast<us4*>(&rb[2048 + t*4]) = hv;
    }
}

// ---------------- softmax stats over fp32 logits ----------------
__global__ void col_stats_partial(const float* __restrict__ logits,
                                  float* __restrict__ pmax, float* __restrict__ psum) {
    int col = blockIdx.x * 256 + threadIdx.x;
    int ch  = blockIdx.y;
    int b   = blockIdx.z;
    const float* base = logits + ((size_t)b * SEQ + (size_t)ch * 512) * ES + col;
    float m = -INFINITY, s = 0.f;
    for (int n = 0; n < 512; ++n) {
        float v = base[(size_t)n * ES];
        float mn = fmaxf(m, v);
        s = s * __expf(m - mn) + __expf(v - mn);
        m = mn;
    }
    size_t idx = ((size_t)b * 8 + ch) * ES + col;
    pmax[idx] = m; psum[idx] = s;
}

__global__ void col_stats_reduce(const float* __restrict__ pmax, const float* __restrict__ psum,
                                 float* __restrict__ cmax, float* __restrict__ cinv) {
    int col = blockIdx.x * 256 + threadIdx.x;
    int b   = blockIdx.y;
    float m = -INFINITY, s = 0.f;
    for (int ch = 0; ch < 8; ++ch) {
        size_t idx = ((size_t)b * 8 + ch) * ES + col;
        float m2 = pmax[idx], s2 = psum[idx];
        float mn = fmaxf(m, m2);
        s = s * __expf(m - mn) + s2 * __expf(m2 - mn);
        m = mn;
    }
    cmax[(size_t)b * ES + col] = m;
    cinv[(size_t)b * ES + col] = 1.0f / s;
}

__global__ void row_stats(const float* __restrict__ logits,
                          float* __restrict__ rmax, float* __restrict__ rinv) {
    int row = blockIdx.x;
    int t = threadIdx.x;
    const float* base = logits + (size_t)row * ES;
    float m = -INFINITY, s = 0.f;
    for (int i = t; i < ES; i += 256) {
        float v = base[i];
        float mn = fmaxf(m, v);
        s = s * __expf(m - mn) + __expf(v - mn);
        m = mn;
    }
    __shared__ float sm[256], ssum[256];
    sm[t] = m; ssum[t] = s;
    __syncthreads();
    for (int off = 128; off >= 1; off >>= 1) {
        if (t < off) {
            float m1 = sm[t], m2 = sm[t+off], s1 = ssum[t], s2 = ssum[t+off];
            float mn = fmaxf(m1, m2);
            sm[t] = mn;
            ssum[t] = s1 * __expf(m1 - mn) + s2 * __expf(m2 - mn);
        }
        __syncthreads();
    }
    if (t == 0) { rmax[row] = sm[0]; rinv[row] = 1.0f / ssum[0]; }
}

// ---------------- fused weights pass: comb (row-major) + dispT (transposed), both bf16 -------
__global__ void make_weights(const float* __restrict__ logits,
                             const float* __restrict__ cmax, const float* __restrict__ cinv,
                             const float* __restrict__ rmax, const float* __restrict__ rinv,
                             unsigned short* __restrict__ comb, unsigned short* __restrict__ dispT) {
    int b = blockIdx.z;
    const float* L = logits + (size_t)b * SEQ * ES;
    int n0 = blockIdx.y * 32, e0 = blockIdx.x * 32;
    int t = threadIdx.x;
    int r = t >> 3, c4 = (t & 7) * 4;
    __shared__ unsigned short tile[32][36];
    float4 v = *reinterpret_cast<const float4*>(&L[(size_t)(n0 + r) * ES + e0 + c4]);
    float rm = rmax[b*SEQ + n0 + r], ri = rinv[b*SEQ + n0 + r];
    float vv[4] = {v.x, v.y, v.z, v.w};
    us4 cb;
    #pragma unroll
    for (int q = 0; q < 4; ++q) {
        cb[q] = f2bf(__expf(vv[q] - rm) * ri);
        float dv = __expf(vv[q] - cmax[b*ES + e0 + c4 + q]) * cinv[b*ES + e0 + c4 + q];
        tile[c4 + q][r] = f2bf(dv);
    }
    *reinterpret_cast<us4*>(&comb[(size_t)b*SEQ*ES + (size_t)(n0 + r)*ES + e0 + c4]) = cb;
    __syncthreads();
    us4 o = *reinterpret_cast<us4*>(&tile[t >> 3][(t & 7) * 4]);
    *reinterpret_cast<us4*>(&dispT[(size_t)b*ES*SEQ + (size_t)(e0 + (t >> 3))*SEQ + n0 + (t & 7)*4]) = o;
}

// ---------------- bf16 -> bf16 transpose (32x32 tiles) ----------------
__global__ void transpose_b16(const unsigned short* __restrict__ src, unsigned short* __restrict__ dst,
                              int sld, int dld, long sStride, long dStride) {
    int z = blockIdx.z;
    const unsigned short* S = src + (size_t)z * sStride;
    unsigned short* D = dst + (size_t)z * dStride;
    int r0 = blockIdx.y * 32, c0 = blockIdx.x * 32;
    int t = threadIdx.x;
    __shared__ unsigned short tile[32][36];
    us4 v = *reinterpret_cast<const us4*>(&S[(size_t)(r0 + (t>>3)) * sld + c0 + (t&7)*4]);
    #pragma unroll
    for (int q = 0; q < 4; ++q) tile[(t&7)*4 + q][t>>3] = v[q];
    __syncthreads();
    us4 o = *reinterpret_cast<us4*>(&tile[t >> 3][(t & 7) * 4]);
    *reinterpret_cast<us4*>(&D[(size_t)(c0 + (t>>3)) * dld + r0 + (t&7)*4]) = o;
}

// ---------------- f32 -> bf16 transpose (32x32 tiles) ----------------
__global__ void transpose_f32_b16(const float* __restrict__ src, unsigned short* __restrict__ dst,
                                  int sld, int dld, long sStride, long dStride) {
    int z = blockIdx.z;
    const float* S = src + (size_t)z * sStride;
    unsigned short* D = dst + (size_t)z * dStride;
    int r0 = blockIdx.y * 32, c0 = blockIdx.x * 32;
    int t = threadIdx.x;
    __shared__ unsigned short tile[32][36];
    float4 v = *reinterpret_cast<const float4*>(&S[(size_t)(r0 + (t>>3)) * sld + c0 + (t&7)*4]);
    float vv[4] = {v.x, v.y, v.z, v.w};
    #pragma unroll
    for (int q = 0; q < 4; ++q) tile[(t&7)*4 + q][t>>3] = f2bf(vv[q]);
    __syncthreads();
    us4 o = *reinterpret_cast<us4*>(&tile[t >> 3][(t & 7) * 4]);
    *reinterpret_cast<us4*>(&D[(size_t)(c0 + (t>>3)) * dld + r0 + (t&7)*4]) = o;
}

// ---------------- MFMA bf16 GEMM: C[M][N] = A[M][K] * B[N][K]^T ----------------
// 128x128 tile, BK=64, 256 threads (4 waves, 2x2), 4x4 16x16x32 frags per wave.
// EPI: 0 none, 1 +bias, 2 +bias+gelu.  OM: 0 f32 row-major, 1 bf16 row-major, 2 bf16 transposed.
template<int EPI, int OM>
__global__ void mfma_gemm(const unsigned short* __restrict__ A, const unsigned short* __restrict__ B,
                          void* __restrict__ Cv, const float* __restrict__ bias,
                          int N, int K, int lda, int ldb, int ldc,
                          long aStride, long bStride, long cStride, long cStrideE, int bMod) {
    __shared__ unsigned short As[128 * 64];
    __shared__ unsigned short Bs[128 * 64];
    int z = blockIdx.z;
    int zb = z % bMod;
    const unsigned short* Ab = A + (size_t)z * aStride;
    const unsigned short* Bb = B + (size_t)zb * bStride;
    int m0 = blockIdx.y * 128, n0 = blockIdx.x * 128;
    int t = threadIdx.x;
    int lane = t & 63, wave = t >> 6;
    int wr = wave >> 1, wc = wave & 1;
    int srow = t >> 3;                 // staging row within a 32-row chunk
    int scol = (t & 7) * 8;            // staging col (elements)
    unsigned short* AsW = As + wave * 512;
    unsigned short* BsW = Bs + wave * 512;

    f32x4 acc[4][4] = {};

    for (int k0 = 0; k0 < K; k0 += 64) {
        #pragma unroll
        for (int j = 0; j < 4; ++j) {
            const unsigned short* ga = Ab + (size_t)(m0 + j*32 + srow) * lda + k0 + scol;
            GLOAD_LDS16(ga, AsW + j*2048);
            const unsigned short* gb = Bb + (size_t)(n0 + j*32 + srow) * ldb + k0 + scol;
            GLOAD_LDS16(gb, BsW + j*2048);
        }
        __syncthreads();
        #pragma unroll
        for (int kk = 0; kk < 2; ++kk) {
            bf16x8 af[4], bfr[4];
            #pragma unroll
            for (int i = 0; i < 4; ++i)
                af[i] = *reinterpret_cast<const bf16x8*>(
                    &As[(wr*64 + i*16 + (lane & 15)) * 64 + kk*32 + (lane >> 4) * 8]);
            #pragma unroll
            for (int jn = 0; jn < 4; ++jn)
                bfr[jn] = *reinterpret_cast<const bf16x8*>(
                    &Bs[(wc*64 + jn*16 + (lane & 15)) * 64 + kk*32 + (lane >> 4) * 8]);
            #pragma unroll
            for (int i = 0; i < 4; ++i)
                #pragma unroll
                for (int jn = 0; jn < 4; ++jn)
                    acc[i][jn] = __builtin_amdgcn_mfma_f32_16x16x32_bf16(af[i], bfr[jn], acc[i][jn], 0, 0, 0);
        }
        __syncthreads();
    }

    const float* bz = (EPI != 0) ? bias + (size_t)zb * N : nullptr;
    long coff = (long)z * cStride + (long)zb * cStrideE;
    int rbase = (lane >> 4) * 4;
    int cbase = lane & 15;
    #pragma unroll
    for (int i = 0; i < 4; ++i) {
        #pragma unroll
        for (int jn = 0; jn < 4; ++jn) {
            int col  = n0 + wc*64 + jn*16 + cbase;
            int row0 = m0 + wr*64 + i*16 + rbase;
            float bv = (EPI != 0) ? bz[col] : 0.f;
            float vals[4];
            #pragma unroll
            for (int r = 0; r < 4; ++r) {
                float v = acc[i][jn][r] + bv;
                if (EPI == 2) v = gelu_exact(v);
                vals[r] = v;
            }
            if (OM == 0) {
                float* C = (float*)Cv + coff;
                #pragma unroll
                for (int r = 0; r < 4; ++r) C[(size_t)(row0 + r) * ldc + col] = vals[r];
            } else if (OM == 1) {
                unsigned short* C = (unsigned short*)Cv + coff;
                #pragma unroll
                for (int r = 0; r < 4; ++r) C[(size_t)(row0 + r) * ldc + col] = f2bf(vals[r]);
            } else {
                unsigned short* C = (unsigned short*)Cv + coff;
                us4 o;
                #pragma unroll
                for (int r = 0; r < 4; ++r) o[r] = f2bf(vals[r]);
                *reinterpret_cast<us4*>(&C[(size_t)col * ldc + row0]) = o;
            }
        }
    }
}

extern "C" void kernel_launch(void* const* d_in, const int* in_sizes, int n_in,
                              void* d_out, int out_size, void* d_ws, size_t ws_size,
                              hipStream_t stream) {
    const float* x    = (const float*)d_in[0];
    const float* ng   = (const float*)d_in[1];
    const float* sg   = (const float*)d_in[2];
    const float* semb = (const float*)d_in[3];
    const float* w1   = (const float*)d_in[4];
    const float* b1   = (const float*)d_in[5];
    const float* w2   = (const float*)d_in[6];
    const float* b2   = (const float*)d_in[7];
    float* out = (float*)d_out;

    // ---- workspace layout with liveness reuse (total ~311 MB) ----
    char* base = (char*)d_ws;
    unsigned short* Acat  = (unsigned short*)(base);               // [8192][3072] bf16 (hi|hi|lo)
    unsigned short* Bcat  = (unsigned short*)(base + 50331648);    // [4096][3072] bf16 (hi|lo|hi)
    unsigned short* dispT = (unsigned short*)(base);               // [2][4096][4096] (reuses Acat+Bcat)
    unsigned short* w2T   = (unsigned short*)(base);               // [8][1024][4096] (reuses dispT)
    float*          logits= (float*)(base + 75497472);             // [2][4096][4096] f32
    unsigned short* hbuf  = (unsigned short*)(base + 75497472);    // [16][512][4096] (reuses logits)
    unsigned short* w1T   = (unsigned short*)(base + 142606336);   // [8][4096][1024] (reuses logits+67MB)
    unsigned short* xnT   = (unsigned short*)(base + 209715200);   // [2][1024][4096]
    unsigned short* comb  = (unsigned short*)(base + 226492416);   // [2][4096][4096]
    unsigned short* slots = (unsigned short*)(base + 293601280);   // [2][4096][1024]
    unsigned short* eoT   = (unsigned short*)(base + 293601280);   // [2][1024][4096] (reuses slots)
    float* pmax = (float*)(base + 310378496);
    float* psum = pmax + 65536;
    float* cmax = psum + 65536;
    float* cinv = cmax + 8192;
    float* rmax = cinv + 8192;
    float* rinv = rmax + 8192;

    // 1. RMSNorm + hi/lo split
    rmsnorm_split<0><<<NB*SEQ, 256, 0, stream>>>(x, ng, Acat);
    rmsnorm_split<1><<<NEXP*NSLOT, 256, 0, stream>>>(semb, sg, Bcat);

    // 2. xnT[b][d][n] = hi(xn) transposed (before Acat is overwritten)
    transpose_b16<<<dim3(DIM/32, SEQ/32, NB), 256, 0, stream>>>(
        Acat, xnT, 3072, SEQ, (long)SEQ*3072, (long)DIM*SEQ);

    // 3. logits = [x_hi|x_hi|x_lo] @ [s_hi|s_lo|s_hi]^T  (bf16x2 split, K=3072)
    mfma_gemm<0,0><<<dim3(ES/128, (NB*SEQ)/128, 1), 256, 0, stream>>>(
        Acat, Bcat, logits, nullptr, ES, 3072, 3072, 3072, ES,
        0L, 0L, 0L, 0L, 1);

    // 4. softmax stats
    col_stats_partial<<<dim3(ES/256, 8, NB), 256, 0, stream>>>(logits, pmax, psum);
    col_stats_reduce<<<dim3(ES/256, NB), 256, 0, stream>>>(pmax, psum, cmax, cinv);
    row_stats<<<NB*SEQ, 256, 0, stream>>>(logits, rmax, rinv);

    // 5. comb[b][n][es] + dispT[b][es][n] (bf16). Acat/Bcat dead.
    make_weights<<<dim3(ES/32, SEQ/32, NB), 256, 0, stream>>>(
        logits, cmax, cinv, rmax, rinv, comb, dispT);

    // 6. w1T[e][hid][dim] (logits dead -> region reused for hbuf+w1T)
    transpose_f32_b16<<<dim3(HID/32, DIM/32, NEXP), 256, 0, stream>>>(
        w1, w1T, HID, DIM, (long)DIM*HID, (long)HID*DIM);

    // 7. slots[b][es][d] = dispT @ xnT^T   M=4096 N=1024 K=4096 (bf16 out)
    mfma_gemm<0,1><<<dim3(DIM/128, ES/128, NB), 256, 0, stream>>>(
        dispT, xnT, slots, nullptr, DIM, SEQ, SEQ, SEQ, DIM,
        (long)ES*SEQ, (long)DIM*SEQ, (long)ES*DIM, 0L, NB);

    // 8. w2T[e][dim][hid] (dispT dead -> region reused)
    transpose_f32_b16<<<dim3(DIM/32, HID/32, NEXP), 256, 0, stream>>>(
        w2, w2T, DIM, HID, (long)HID*DIM, (long)DIM*HID);

    // 9. FF1: h = gelu(slots @ w1T^T + b1)  z=(b,e)  M=512 N=4096 K=1024 (bf16 out)
    mfma_gemm<2,1><<<dim3(HID/128, NSLOT/128, NB*NEXP), 256, 0, stream>>>(
        slots, w1T, hbuf, b1, HID, DIM, DIM, DIM, HID,
        (long)NSLOT*DIM, (long)HID*DIM, (long)NSLOT*HID, 0L, NEXP);

    // 10. FF2: eoT[b][d][e*512+s] = (h @ w2T^T + b2)^T  M=512 N=1024 K=4096 (bf16 transposed out)
    mfma_gemm<1,2><<<dim3(DIM/128, NSLOT/128, NB*NEXP), 256, 0, stream>>>(
        hbuf, w2T, eoT, b2, DIM, HID, HID, HID, ES,
        (long)NSLOT*HID, (long)DIM*HID, (long)(DIM*ES/NEXP), (long)(NSLOT - DIM*ES/NEXP), NEXP);

    // 11. out[b][n][d] = comb @ eoT^T   M=4096 N=1024 K=4096 (f32 out)
    mfma_gemm<0,0><<<dim3(DIM/128, SEQ/128, NB), 256, 0, stream>>>(
        comb, eoT, out, nullptr, DIM, ES, ES, ES, DIM,
        (long)SEQ*ES, (long)DIM*ES, (long)SEQ*DIM, 0L, NB);
}

// Round 3
// 833.293 us; speedup vs baseline: 5.5175x; 1.0385x over previous
//
#include <hip/hip_runtime.h>
#include <math.h>

#define SEQ    4096
#define DIM    1024
#define NEXP   8
#define NSLOT  512
#define ES     4096
#define HID    4096
#define NB     2
#define RMS_SCALE 32.0f

typedef __attribute__((ext_vector_type(4))) float f32x4;
typedef __attribute__((ext_vector_type(8))) short bf16x8;
typedef __attribute__((ext_vector_type(4))) unsigned short us4;

__device__ __forceinline__ unsigned short f2bf(float f) {
    unsigned u = __float_as_uint(f);
    u += 0x7fff + ((u >> 16) & 1);          // round-to-nearest-even
    return (unsigned short)(u >> 16);
}
__device__ __forceinline__ float bf2f(unsigned short h) {
    return __uint_as_float(((unsigned)h) << 16);
}
__device__ __forceinline__ float gelu_exact(float x) {
    return 0.5f * x * (1.0f + erff(x * 0.70710678118654752f));
}

#define GLOAD_LDS16(gp, lp) \
    __builtin_amdgcn_global_load_lds((const __attribute__((address_space(1))) void*)(gp), \
                                     (__attribute__((address_space(3))) void*)(lp), 16, 0, 0)

__device__ __forceinline__ unsigned ldsoff(const void* p) {
    return (unsigned)(size_t)(const __attribute__((address_space(3))) void*)p;
}

#define DSR(dst, base, off) asm volatile("ds_read_b128 %0, %1 offset:" off : "=v"(dst) : "v"(base))

// ---------------- RMSNorm + bf16 hi/lo split into K-concat layout ----------------
template<int ORDER>
__global__ void rmsnorm_split(const float* __restrict__ in, const float* __restrict__ gamma,
                              unsigned short* __restrict__ outc) {
    int row = blockIdx.x;
    int t = threadIdx.x;
    float4 v = reinterpret_cast<const float4*>(in + (size_t)row * DIM)[t];
    float ss = v.x*v.x + v.y*v.y + v.z*v.z + v.w*v.w;
    #pragma unroll
    for (int off = 32; off >= 1; off >>= 1) ss += __shfl_down(ss, off, 64);
    __shared__ float red[4];
    if ((t & 63) == 0) red[t >> 6] = ss;
    __syncthreads();
    float inv = RMS_SCALE / fmaxf(sqrtf(red[0] + red[1] + red[2] + red[3]), 1e-12f);
    float4 g = reinterpret_cast<const float4*>(gamma)[t];
    float f[4] = {v.x*inv*g.x, v.y*inv*g.y, v.z*inv*g.z, v.w*inv*g.w};
    us4 hv, lv;
    #pragma unroll
    for (int q = 0; q < 4; ++q) {
        unsigned short h = f2bf(f[q]);
        hv[q] = h;
        lv[q] = f2bf(f[q] - bf2f(h));
    }
    unsigned short* rb = outc + (size_t)row * 3072;
    *reinterpret_cast<us4*>(&rb[t*4]) = hv;
    if (ORDER == 0) {
        *reinterpret_cast<us4*>(&rb[1024 + t*4]) = hv;
        *reinterpret_cast<us4*>(&rb[2048 + t*4]) = lv;
    } else {
        *reinterpret_cast<us4*>(&rb[1024 + t*4]) = lv;
        *reinterpret_cast<us4*>(&rb[2048 + t*4]) = hv;
    }
}

// ---------------- softmax stats over fp32 logits ----------------
__global__ void col_stats_partial(const float* __restrict__ logits,
                                  float* __restrict__ pmax, float* __restrict__ psum) {
    int col = blockIdx.x * 256 + threadIdx.x;
    int ch  = blockIdx.y;
    int b   = blockIdx.z;
    const float* base = logits + ((size_t)b * SEQ + (size_t)ch * 512) * ES + col;
    float m = -INFINITY, s = 0.f;
    for (int n = 0; n < 512; ++n) {
        float v = base[(size_t)n * ES];
        float mn = fmaxf(m, v);
        s = s * __expf(m - mn) + __expf(v - mn);
        m = mn;
    }
    size_t idx = ((size_t)b * 8 + ch) * ES + col;
    pmax[idx] = m; psum[idx] = s;
}

__global__ void col_stats_reduce(const float* __restrict__ pmax, const float* __restrict__ psum,
                                 float* __restrict__ cmax, float* __restrict__ cinv) {
    int col = blockIdx.x * 256 + threadIdx.x;
    int b   = blockIdx.y;
    float m = -INFINITY, s = 0.f;
    for (int ch = 0; ch < 8; ++ch) {
        size_t idx = ((size_t)b * 8 + ch) * ES + col;
        float m2 = pmax[idx], s2 = psum[idx];
        float mn = fmaxf(m, m2);
        s = s * __expf(m - mn) + s2 * __expf(m2 - mn);
        m = mn;
    }
    cmax[(size_t)b * ES + col] = m;
    cinv[(size_t)b * ES + col] = 1.0f / s;
}

__global__ void row_stats(const float* __restrict__ logits,
                          float* __restrict__ rmax, float* __restrict__ rinv) {
    int row = blockIdx.x;
    int t = threadIdx.x;
    const float* base = logits + (size_t)row * ES;
    float m = -INFINITY, s = 0.f;
    for (int i = t; i < ES; i += 256) {
        float v = base[i];
        float mn = fmaxf(m, v);
        s = s * __expf(m - mn) + __expf(v - mn);
        m = mn;
    }
    __shared__ float sm[256], ssum[256];
    sm[t] = m; ssum[t] = s;
    __syncthreads();
    for (int off = 128; off >= 1; off >>= 1) {
        if (t < off) {
            float m1 = sm[t], m2 = sm[t+off], s1 = ssum[t], s2 = ssum[t+off];
            float mn = fmaxf(m1, m2);
            sm[t] = mn;
            ssum[t] = s1 * __expf(m1 - mn) + s2 * __expf(m2 - mn);
        }
        __syncthreads();
    }
    if (t == 0) { rmax[row] = sm[0]; rinv[row] = 1.0f / ssum[0]; }
}

// ---------------- fused weights pass ----------------
__global__ void make_weights(const float* __restrict__ logits,
                             const float* __restrict__ cmax, const float* __restrict__ cinv,
                             const float* __restrict__ rmax, const float* __restrict__ rinv,
                             unsigned short* __restrict__ comb, unsigned short* __restrict__ dispT) {
    int b = blockIdx.z;
    const float* L = logits + (size_t)b * SEQ * ES;
    int n0 = blockIdx.y * 32, e0 = blockIdx.x * 32;
    int t = threadIdx.x;
    int r = t >> 3, c4 = (t & 7) * 4;
    __shared__ unsigned short tile[32][36];
    float4 v = *reinterpret_cast<const float4*>(&L[(size_t)(n0 + r) * ES + e0 + c4]);
    float rm = rmax[b*SEQ + n0 + r], ri = rinv[b*SEQ + n0 + r];
    float vv[4] = {v.x, v.y, v.z, v.w};
    us4 cb;
    #pragma unroll
    for (int q = 0; q < 4; ++q) {
        cb[q] = f2bf(__expf(vv[q] - rm) * ri);
        float dv = __expf(vv[q] - cmax[b*ES + e0 + c4 + q]) * cinv[b*ES + e0 + c4 + q];
        tile[c4 + q][r] = f2bf(dv);
    }
    *reinterpret_cast<us4*>(&comb[(size_t)b*SEQ*ES + (size_t)(n0 + r)*ES + e0 + c4]) = cb;
    __syncthreads();
    us4 o = *reinterpret_cast<us4*>(&tile[t >> 3][(t & 7) * 4]);
    *reinterpret_cast<us4*>(&dispT[(size_t)b*ES*SEQ + (size_t)(e0 + (t >> 3))*SEQ + n0 + (t & 7)*4]) = o;
}

// ---------------- bf16 -> bf16 transpose ----------------
__global__ void transpose_b16(const unsigned short* __restrict__ src, unsigned short* __restrict__ dst,
                              int sld, int dld, long sStride, long dStride) {
    int z = blockIdx.z;
    const unsigned short* S = src + (size_t)z * sStride;
    unsigned short* D = dst + (size_t)z * dStride;
    int r0 = blockIdx.y * 32, c0 = blockIdx.x * 32;
    int t = threadIdx.x;
    __shared__ unsigned short tile[32][36];
    us4 v = *reinterpret_cast<const us4*>(&S[(size_t)(r0 + (t>>3)) * sld + c0 + (t&7)*4]);
    #pragma unroll
    for (int q = 0; q < 4; ++q) tile[(t&7)*4 + q][t>>3] = v[q];
    __syncthreads();
    us4 o = *reinterpret_cast<us4*>(&tile[t >> 3][(t & 7) * 4]);
    *reinterpret_cast<us4*>(&D[(size_t)(c0 + (t>>3)) * dld + r0 + (t&7)*4]) = o;
}

// ---------------- f32 -> bf16 transpose ----------------
__global__ void transpose_f32_b16(const float* __restrict__ src, unsigned short* __restrict__ dst,
                                  int sld, int dld, long sStride, long dStride) {
    int z = blockIdx.z;
    const float* S = src + (size_t)z * sStride;
    unsigned short* D = dst + (size_t)z * dStride;
    int r0 = blockIdx.y * 32, c0 = blockIdx.x * 32;
    int t = threadIdx.x;
    __shared__ unsigned short tile[32][36];
    float4 v = *reinterpret_cast<const float4*>(&S[(size_t)(r0 + (t>>3)) * sld + c0 + (t&7)*4]);
    float vv[4] = {v.x, v.y, v.z, v.w};
    #pragma unroll
    for (int q = 0; q < 4; ++q) tile[(t&7)*4 + q][t>>3] = f2bf(vv[q]);
    __syncthreads();
    us4 o = *reinterpret_cast<us4*>(&tile[t >> 3][(t & 7) * 4]);
    *reinterpret_cast<us4*>(&D[(size_t)(c0 + (t>>3)) * dld + r0 + (t&7)*4]) = o;
}

// ---------------- m97-style 128x128 MFMA GEMM (kept for slots/FF2/out) ----------------
template<int EPI, int OM>
__global__ void mfma_gemm(const unsigned short* __restrict__ A, const unsigned short* __restrict__ B,
                          void* __restrict__ Cv, const float* __restrict__ bias,
                          int N, int K, int lda, int ldb, int ldc,
                          long aStride, long bStride, long cStride, long cStrideE, int bMod) {
    __shared__ unsigned short As[128 * 64];
    __shared__ unsigned short Bs[128 * 64];
    int z = blockIdx.z;
    int zb = z % bMod;
    const unsigned short* Ab = A + (size_t)z * aStride;
    const unsigned short* Bb = B + (size_t)zb * bStride;
    int m0 = blockIdx.y * 128, n0 = blockIdx.x * 128;
    int t = threadIdx.x;
    int lane = t & 63, wave = t >> 6;
    int wr = wave >> 1, wc = wave & 1;
    int srow = t >> 3;
    int scol = (t & 7) * 8;
    unsigned short* AsW = As + wave * 512;
    unsigned short* BsW = Bs + wave * 512;

    f32x4 acc[4][4] = {};

    for (int k0 = 0; k0 < K; k0 += 64) {
        #pragma unroll
        for (int j = 0; j < 4; ++j) {
            const unsigned short* ga = Ab + (size_t)(m0 + j*32 + srow) * lda + k0 + scol;
            GLOAD_LDS16(ga, AsW + j*2048);
            const unsigned short* gb = Bb + (size_t)(n0 + j*32 + srow) * ldb + k0 + scol;
            GLOAD_LDS16(gb, BsW + j*2048);
        }
        __syncthreads();
        #pragma unroll
        for (int kk = 0; kk < 2; ++kk) {
            bf16x8 af[4], bfr[4];
            #pragma unroll
            for (int i = 0; i < 4; ++i)
                af[i] = *reinterpret_cast<const bf16x8*>(
                    &As[(wr*64 + i*16 + (lane & 15)) * 64 + kk*32 + (lane >> 4) * 8]);
            #pragma unroll
            for (int jn = 0; jn < 4; ++jn)
                bfr[jn] = *reinterpret_cast<const bf16x8*>(
                    &Bs[(wc*64 + jn*16 + (lane & 15)) * 64 + kk*32 + (lane >> 4) * 8]);
            #pragma unroll
            for (int i = 0; i < 4; ++i)
                #pragma unroll
                for (int jn = 0; jn < 4; ++jn)
                    acc[i][jn] = __builtin_amdgcn_mfma_f32_16x16x32_bf16(af[i], bfr[jn], acc[i][jn], 0, 0, 0);
        }
        __syncthreads();
    }

    const float* bz = (EPI != 0) ? bias + (size_t)zb * N : nullptr;
    long coff = (long)z * cStride + (long)zb * cStrideE;
    int rbase = (lane >> 4) * 4;
    int cbase = lane & 15;
    #pragma unroll
    for (int i = 0; i < 4; ++i) {
        #pragma unroll
        for (int jn = 0; jn < 4; ++jn) {
            int col  = n0 + wc*64 + jn*16 + cbase;
            int row0 = m0 + wr*64 + i*16 + rbase;
            float bv = (EPI != 0) ? bz[col] : 0.f;
            float vals[4];
            #pragma unroll
            for (int r = 0; r < 4; ++r) {
                float v = acc[i][jn][r] + bv;
                if (EPI == 2) v = gelu_exact(v);
                vals[r] = v;
            }
            if (OM == 0) {
                float* C = (float*)Cv + coff;
                #pragma unroll
                for (int r = 0; r < 4; ++r) C[(size_t)(row0 + r) * ldc + col] = vals[r];
            } else if (OM == 1) {
                unsigned short* C = (unsigned short*)Cv + coff;
                #pragma unroll
                for (int r = 0; r < 4; ++r) C[(size_t)(row0 + r) * ldc + col] = f2bf(vals[r]);
            } else {
                unsigned short* C = (unsigned short*)Cv + coff;
                us4 o;
                #pragma unroll
                for (int r = 0; r < 4; ++r) o[r] = f2bf(vals[r]);
                *reinterpret_cast<us4*>(&C[(size_t)col * ldc + row0]) = o;
            }
        }
    }
}

// ================= 256x256 8-phase MFMA GEMM (T2+T3+T4+T5) =================
// C[M][N] = A[M][K] * B[N][K]^T. BK=64, 512 thr = 8 waves (2M x 4N),
// per-wave 128x64 C (acc[8][4]). LDS 128KB: [buf][A 32KB | B 32KB] x2.
// Swizzle: 16B-slot = (col>>3) ^ (row&7); linear LDS dest + pre-swizzled
// global source (rule #21). Staging: 1 half-tile (2x gload_lds 8KB) per phase:
//   P1,P2: A(t+1)->buf1   P3,P4: B(t+2)->buf0   P5,P6: A(t+2)->buf0
//   P7,P8: B(t+3)->buf1;  vmcnt(4) at P4/P8 (vmcnt(0) in last iteration).
template<int EPI, int OM>
__global__ __launch_bounds__(512, 2)
void mfma_gemm256(const unsigned short* __restrict__ A, const unsigned short* __restrict__ B,
                  void* __restrict__ Cv, const float* __restrict__ bias,
                  int N, int K, int lda, int ldb, int ldc,
                  long aStride, long bStride, long cStride, int bMod) {
    __shared__ unsigned short lds[65536];   // 128 KB
    const int t = threadIdx.x;
    const int lane = t & 63, wave = t >> 6;
    const int wr = wave >> 2, wc = wave & 3;
    const int z = blockIdx.z, zb = z % bMod;
    const unsigned short* Ab = A + (size_t)z * aStride;
    const unsigned short* Bb = B + (size_t)zb * bStride;
    const int m0 = blockIdx.y * 256, n0 = blockIdx.x * 256;

    // staging: per-thread source (pre-swizzled) — row sr, logical 16B-group sg
    const int sr = t >> 3;
    const int sg = (t & 7) ^ (sr & 7);
    const unsigned short* gA = Ab + (size_t)(m0 + sr) * lda + sg * 8;
    const unsigned short* gB = Bb + (size_t)(n0 + sr) * ldb + sg * 8;
    unsigned short* ldsw = lds + wave * 512;   // wave-uniform stage base (elements)

    // lds element regions: A(buf)=buf*32768, B(buf)=buf*32768+16384
    // ds_read byte bases (swizzled); row&7 == lr&7 for all frags
    const int lr = lane & 15, lk = lane >> 4;
    const unsigned sw0 = (unsigned)(((lk)     ^ (lr & 7)) << 4);   // kk=0
    const unsigned sw1 = (unsigned)(((4 + lk) ^ (lr & 7)) << 4);   // kk=1
    const unsigned l0  = ldsoff(lds);
    const unsigned arow = (unsigned)((wr*128 + lr) * 128);
    const unsigned brow = (unsigned)((wc*64  + lr) * 128);
    const unsigned ab00 = l0 + arow + sw0,          ab10 = l0 + arow + sw1;
    const unsigned bb00 = l0 + 32768 + brow + sw0,  bb10 = l0 + 32768 + brow + sw1;
    const unsigned ab01 = ab00 + 65536, ab11 = ab10 + 65536;
    const unsigned bb01 = bb00 + 65536, bb11 = bb10 + 65536;

    #define STAGE_A(buf, half, tt) do { \
        const unsigned short* _g = gA + (size_t)((half)*128) * lda + (tt)*64; \
        unsigned short* _l = ldsw + (buf)*32768 + (half)*8192; \
        GLOAD_LDS16(_g, _l); \
        GLOAD_LDS16(_g + (size_t)64*lda, _l + 4096); } while(0)
    #define STAGE_B(buf, half, tt) do { \
        const unsigned short* _g = gB + (size_t)((half)*128) * ldb + (tt)*64; \
        unsigned short* _l = ldsw + (buf)*32768 + 16384 + (half)*8192; \
        GLOAD_LDS16(_g, _l); \
        GLOAD_LDS16(_g + (size_t)64*ldb, _l + 4096); } while(0)

    f32x4 acc[8][4] = {};
    bf16x8 a0[4], a1[4], b0[4], b1[4];

    const int NT = K / 64;

    // prologue: K0 full + K1's B
    STAGE_B(0, 0, 0); STAGE_B(0, 1, 0);
    STAGE_A(0, 0, 0); STAGE_A(0, 1, 0);
    STAGE_B(1, 0, 1); STAGE_B(1, 1, 1);
    asm volatile("s_waitcnt vmcnt(4)" ::: "memory");
    __builtin_amdgcn_s_barrier();

    #define PHASE_MFMA(MB, NB_) \
        __builtin_amdgcn_s_barrier(); \
        asm volatile("s_waitcnt lgkmcnt(0)" ::: "memory"); \
        __builtin_amdgcn_sched_barrier(0); \
        __builtin_amdgcn_s_setprio(1); \
        _Pragma("unroll") \
        for (int m = 0; m < 4; ++m) { \
            _Pragma("unroll") \
            for (int n = 0; n < 2; ++n) { \
                acc[MB+m][NB_+n] = __builtin_amdgcn_mfma_f32_16x16x32_bf16(a0[m], b0[NB_+n], acc[MB+m][NB_+n], 0, 0, 0); \
                acc[MB+m][NB_+n] = __builtin_amdgcn_mfma_f32_16x16x32_bf16(a1[m], b1[NB_+n], acc[MB+m][NB_+n], 0, 0, 0); \
            } \
        } \
        __builtin_amdgcn_s_setprio(0); \
        __builtin_amdgcn_sched_barrier(0); \
        __builtin_amdgcn_s_barrier();

    for (int tt = 0; tt < NT; tt += 2) {
        const bool pf = (tt + 2 < NT);
        // ---- P1: reads buf0 A m0-3 + B n0-1; stage Ah0(t+1)->buf1
        DSR(a0[0], ab00, "0");    DSR(a0[1], ab00, "2048");
        DSR(a0[2], ab00, "4096"); DSR(a0[3], ab00, "6144");
        DSR(a1[0], ab10, "0");    DSR(a1[1], ab10, "2048");
        DSR(a1[2], ab10, "4096"); DSR(a1[3], ab10, "6144");
        DSR(b0[0], bb00, "0");    DSR(b0[1], bb00, "2048");
        DSR(b1[0], bb10, "0");    DSR(b1[1], bb10, "2048");
        STAGE_A(1, 0, tt+1);
        __builtin_amdgcn_sched_barrier(0);
        PHASE_MFMA(0, 0)
        // ---- P2: reads B n2-3; stage Ah1(t+1)->buf1
        DSR(b0[2], bb00, "4096"); DSR(b0[3], bb00, "6144");
        DSR(b1[2], bb10, "4096"); DSR(b1[3], bb10, "6144");
        STAGE_A(1, 1, tt+1);
        __builtin_amdgcn_sched_barrier(0);
        PHASE_MFMA(0, 2)
        // ---- P3: reads A m4-7; stage Bh0(t+2)->buf0
        DSR(a0[0], ab00, "8192");  DSR(a0[1], ab00, "10240");
        DSR(a0[2], ab00, "12288"); DSR(a0[3], ab00, "14336");
        DSR(a1[0], ab10, "8192");  DSR(a1[1], ab10, "10240");
        DSR(a1[2], ab10, "12288"); DSR(a1[3], ab10, "14336");
        if (pf) STAGE_B(0, 0, tt+2);
        __builtin_amdgcn_sched_barrier(0);
        PHASE_MFMA(4, 0)
        // ---- P4: no reads; stage Bh1(t+2)->buf0; vmcnt
        if (pf) STAGE_B(0, 1, tt+2);
        __builtin_amdgcn_sched_barrier(0);
        __builtin_amdgcn_s_barrier();
        __builtin_amdgcn_sched_barrier(0);
        __builtin_amdgcn_s_setprio(1);
        #pragma unroll
        for (int m = 0; m < 4; ++m) {
            #pragma unroll
            for (int n = 0; n < 2; ++n) {
                acc[4+m][2+n] = __builtin_amdgcn_mfma_f32_16x16x32_bf16(a0[m], b0[2+n], acc[4+m][2+n], 0, 0, 0);
                acc[4+m][2+n] = __builtin_amdgcn_mfma_f32_16x16x32_bf16(a1[m], b1[2+n], acc[4+m][2+n], 0, 0, 0);
            }
        }
        __builtin_amdgcn_s_setprio(0);
        if (pf) { asm volatile("s_waitcnt vmcnt(4)" ::: "memory"); }
        else    { asm volatile("s_waitcnt vmcnt(0)" ::: "memory"); }
        __builtin_amdgcn_sched_barrier(0);
        __builtin_amdgcn_s_barrier();
        // ---- P5: reads buf1 A m0-3 + B n0-1; stage Ah0(t+2)->buf0
        DSR(a0[0], ab01, "0");    DSR(a0[1], ab01, "2048");
        DSR(a0[2], ab01, "4096"); DSR(a0[3], ab01, "6144");
        DSR(a1[0], ab11, "0");    DSR(a1[1], ab11, "2048");
        DSR(a1[2], ab11, "4096"); DSR(a1[3], ab11, "6144");
        DSR(b0[0], bb01, "0");    DSR(b0[1], bb01, "2048");
        DSR(b1[0], bb11, "0");    DSR(b1[1], bb11, "2048");
        if (pf) STAGE_A(0, 0, tt+2);
        __builtin_amdgcn_sched_barrier(0);
        PHASE_MFMA(0, 0)
        // ---- P6: reads B n2-3; stage Ah1(t+2)->buf0
        DSR(b0[2], bb01, "4096"); DSR(b0[3], bb01, "6144");
        DSR(b1[2], bb11, "4096"); DSR(b1[3], bb11, "6144");
        if (pf) STAGE_A(0, 1, tt+2);
        __builtin_amdgcn_sched_barrier(0);
        PHASE_MFMA(0, 2)
        // ---- P7: reads A m4-7; stage Bh0(t+3)->buf1
        DSR(a0[0], ab01, "8192");  DSR(a0[1], ab01, "10240");
        DSR(a0[2], ab01, "12288"); DSR(a0[3], ab01, "14336");
        DSR(a1[0], ab11, "8192");  DSR(a1[1], ab11, "10240");
        DSR(a1[2], ab11, "12288"); DSR(a1[3], ab11, "14336");
        if (pf) STAGE_B(1, 0, tt+3);
        __builtin_amdgcn_sched_barrier(0);
        PHASE_MFMA(4, 0)
        // ---- P8: no reads; stage Bh1(t+3)->buf1; vmcnt
        if (pf) STAGE_B(1, 1, tt+3);
        __builtin_amdgcn_sched_barrier(0);
        __builtin_amdgcn_s_barrier();
        __builtin_amdgcn_sched_barrier(0);
        __builtin_amdgcn_s_setprio(1);
        #pragma unroll
        for (int m = 0; m < 4; ++m) {
            #pragma unroll
            for (int n = 0; n < 2; ++n) {
                acc[4+m][2+n] = __builtin_amdgcn_mfma_f32_16x16x32_bf16(a0[m], b0[2+n], acc[4+m][2+n], 0, 0, 0);
                acc[4+m][2+n] = __builtin_amdgcn_mfma_f32_16x16x32_bf16(a1[m], b1[2+n], acc[4+m][2+n], 0, 0, 0);
            }
        }
        __builtin_amdgcn_s_setprio(0);
        if (pf) { asm volatile("s_waitcnt vmcnt(4)" ::: "memory"); }
        else    { asm volatile("s_waitcnt vmcnt(0)" ::: "memory"); }
        __builtin_amdgcn_sched_barrier(0);
        __builtin_amdgcn_s_barrier();
    }

    // ---- epilogue ----
    const float* bz = (EPI != 0) ? bias + (size_t)zb * N : nullptr;
    long coff = (long)z * cStride;
    int rbase = (lane >> 4) * 4;
    int cbase = lane & 15;
    #pragma unroll
    for (int f = 0; f < 8; ++f) {
        #pragma unroll
        for (int n = 0; n < 4; ++n) {
            int col  = n0 + wc*64 + n*16 + cbase;
            int row0 = m0 + wr*128 + f*16 + rbase;
            float bv = (EPI != 0) ? bz[col] : 0.f;
            float vals[4];
            #pragma unroll
            for (int r = 0; r < 4; ++r) {
                float v = acc[f][n][r] + bv;
                if (EPI == 2) v = gelu_exact(v);
                vals[r] = v;
            }
            if (OM == 0) {
                float* C = (float*)Cv + coff;
                #pragma unroll
                for (int r = 0; r < 4; ++r) C[(size_t)(row0 + r) * ldc + col] = vals[r];
            } else {
                unsigned short* C = (unsigned short*)Cv + coff;
                #pragma unroll
                for (int r = 0; r < 4; ++r) C[(size_t)(row0 + r) * ldc + col] = f2bf(vals[r]);
            }
        }
    }
    #undef STAGE_A
    #undef STAGE_B
    #undef PHASE_MFMA
}

extern "C" void kernel_launch(void* const* d_in, const int* in_sizes, int n_in,
                              void* d_out, int out_size, void* d_ws, size_t ws_size,
                              hipStream_t stream) {
    const float* x    = (const float*)d_in[0];
    const float* ng   = (const float*)d_in[1];
    const float* sg   = (const float*)d_in[2];
    const float* semb = (const float*)d_in[3];
    const float* w1   = (const float*)d_in[4];
    const float* b1   = (const float*)d_in[5];
    const float* w2   = (const float*)d_in[6];
    const float* b2   = (const float*)d_in[7];
    float* out = (float*)d_out;

    // ---- workspace layout with liveness reuse (total ~311 MB) ----
    char* base = (char*)d_ws;
    unsigned short* Acat  = (unsigned short*)(base);               // [8192][3072] bf16 (hi|hi|lo)
    unsigned short* Bcat  = (unsigned short*)(base + 50331648);    // [4096][3072] bf16 (hi|lo|hi)
    unsigned short* dispT = (unsigned short*)(base);               // [2][4096][4096] (reuses Acat+Bcat)
    unsigned short* w2T   = (unsigned short*)(base);               // [8][1024][4096] (reuses dispT)
    float*          logits= (float*)(base + 75497472);             // [2][4096][4096] f32
    unsigned short* hbuf  = (unsigned short*)(base + 75497472);    // [16][512][4096] (reuses logits)
    unsigned short* w1T   = (unsigned short*)(base + 142606336);   // [8][4096][1024] (reuses logits+67MB)
    unsigned short* xnT   = (unsigned short*)(base + 209715200);   // [2][1024][4096]
    unsigned short* comb  = (unsigned short*)(base + 226492416);   // [2][4096][4096]
    unsigned short* slots = (unsigned short*)(base + 293601280);   // [2][4096][1024]
    unsigned short* eoT   = (unsigned short*)(base + 293601280);   // [2][1024][4096] (reuses slots)
    float* pmax = (float*)(base + 310378496);
    float* psum = pmax + 65536;
    float* cmax = psum + 65536;
    float* cinv = cmax + 8192;
    float* rmax = cinv + 8192;
    float* rinv = rmax + 8192;

    // 1. RMSNorm + hi/lo split
    rmsnorm_split<0><<<NB*SEQ, 256, 0, stream>>>(x, ng, Acat);
    rmsnorm_split<1><<<NEXP*NSLOT, 256, 0, stream>>>(semb, sg, Bcat);

    // 2. xnT[b][d][n] = hi(xn) transposed (before Acat is overwritten)
    transpose_b16<<<dim3(DIM/32, SEQ/32, NB), 256, 0, stream>>>(
        Acat, xnT, 3072, SEQ, (long)SEQ*3072, (long)DIM*SEQ);

    // 3. logits = [x_hi|x_hi|x_lo] @ [s_hi|s_lo|s_hi]^T  (bf16x2 split, K=3072) — 8-phase 256²
    mfma_gemm256<0,0><<<dim3(ES/256, (NB*SEQ)/256, 1), 512, 0, stream>>>(
        Acat, Bcat, logits, nullptr, ES, 3072, 3072, 3072, ES,
        0L, 0L, 0L, 1);

    // 4. softmax stats
    col_stats_partial<<<dim3(ES/256, 8, NB), 256, 0, stream>>>(logits, pmax, psum);
    col_stats_reduce<<<dim3(ES/256, NB), 256, 0, stream>>>(pmax, psum, cmax, cinv);
    row_stats<<<NB*SEQ, 256, 0, stream>>>(logits, rmax, rinv);

    // 5. comb[b][n][es] + dispT[b][es][n] (bf16). Acat/Bcat dead.
    make_weights<<<dim3(ES/32, SEQ/32, NB), 256, 0, stream>>>(
        logits, cmax, cinv, rmax, rinv, comb, dispT);

    // 6. w1T[e][hid][dim] (logits dead -> region reused for hbuf+w1T)
    transpose_f32_b16<<<dim3(HID/32, DIM/32, NEXP), 256, 0, stream>>>(
        w1, w1T, HID, DIM, (long)DIM*HID, (long)HID*DIM);

    // 7. slots[b][es][d] = dispT @ xnT^T   M=4096 N=1024 K=4096 (bf16 out)
    mfma_gemm<0,1><<<dim3(DIM/128, ES/128, NB), 256, 0, stream>>>(
        dispT, xnT, slots, nullptr, DIM, SEQ, SEQ, SEQ, DIM,
        (long)ES*SEQ, (long)DIM*SEQ, (long)ES*DIM, 0L, NB);

    // 8. w2T[e][dim][hid] (dispT dead -> region reused)
    transpose_f32_b16<<<dim3(DIM/32, HID/32, NEXP), 256, 0, stream>>>(
        w2, w2T, DIM, HID, (long)HID*DIM, (long)DIM*HID);

    // 9. FF1: h = gelu(slots @ w1T^T + b1)  z=(b,e)  M=512 N=4096 K=1024 — 8-phase 256²
    mfma_gemm256<2,1><<<dim3(HID/256, NSLOT/256, NB*NEXP), 512, 0, stream>>>(
        slots, w1T, hbuf, b1, HID, DIM, DIM, DIM, HID,
        (long)NSLOT*DIM, (long)HID*DIM, (long)NSLOT*HID, NEXP);

    // 10. FF2: eoT[b][d][e*512+s] = (h @ w2T^T + b2)^T  M=512 N=1024 K=4096 (bf16 transposed out)
    mfma_gemm<1,2><<<dim3(DIM/128, NSLOT/128, NB*NEXP), 256, 0, stream>>>(
        hbuf, w2T, eoT, b2, DIM, HID, HID, HID, ES,
        (long)NSLOT*HID, (long)DIM*HID, (long)(DIM*ES/NEXP), (long)(NSLOT - DIM*ES/NEXP), NEXP);

    // 11. out[b][n][d] = comb @ eoT^T   M=4096 N=1024 K=4096 (f32 out)
    mfma_gemm<0,0><<<dim3(DIM/128, SEQ/128, NB), 256, 0, stream>>>(
        comb, eoT, out, nullptr, DIM, ES, ES, ES, DIM,
        (long)SEQ*ES, (long)DIM*ES, (long)SEQ*DIM, 0L, NB);
}

// Round 4
// 720.146 us; speedup vs baseline: 6.3844x; 1.1571x over previous
//
#include <hip/hip_runtime.h>
#include <math.h>

#define SEQ    4096
#define DIM    1024
#define NEXP   8
#define NSLOT  512
#define ES     4096
#define HID    4096
#define NB     2
#define RMS_SCALE 32.0f

typedef __attribute__((ext_vector_type(4))) float f32x4;
typedef __attribute__((ext_vector_type(8))) short bf16x8;
typedef __attribute__((ext_vector_type(4))) unsigned short us4;

__device__ __forceinline__ unsigned short f2bf(float f) {
    unsigned u = __float_as_uint(f);
    u += 0x7fff + ((u >> 16) & 1);          // round-to-nearest-even
    return (unsigned short)(u >> 16);
}
__device__ __forceinline__ float bf2f(unsigned short h) {
    return __uint_as_float(((unsigned)h) << 16);
}
__device__ __forceinline__ float gelu_exact(float x) {
    return 0.5f * x * (1.0f + erff(x * 0.70710678118654752f));
}

#define GLOAD_LDS16(gp, lp) \
    __builtin_amdgcn_global_load_lds((const __attribute__((address_space(1))) void*)(gp), \
                                     (__attribute__((address_space(3))) void*)(lp), 16, 0, 0)

__device__ __forceinline__ unsigned ldsoff(const void* p) {
    return (unsigned)(size_t)(const __attribute__((address_space(3))) void*)p;
}

#define DSR(dst, base, off) asm volatile("ds_read_b128 %0, %1 offset:" off : "=v"(dst) : "v"(base))

// ---------------- RMSNorm + bf16 hi/lo split into K-concat layout ----------------
template<int ORDER>
__global__ void rmsnorm_split(const float* __restrict__ in, const float* __restrict__ gamma,
                              unsigned short* __restrict__ outc) {
    int row = blockIdx.x;
    int t = threadIdx.x;
    float4 v = reinterpret_cast<const float4*>(in + (size_t)row * DIM)[t];
    float ss = v.x*v.x + v.y*v.y + v.z*v.z + v.w*v.w;
    #pragma unroll
    for (int off = 32; off >= 1; off >>= 1) ss += __shfl_down(ss, off, 64);
    __shared__ float red[4];
    if ((t & 63) == 0) red[t >> 6] = ss;
    __syncthreads();
    float inv = RMS_SCALE / fmaxf(sqrtf(red[0] + red[1] + red[2] + red[3]), 1e-12f);
    float4 g = reinterpret_cast<const float4*>(gamma)[t];
    float f[4] = {v.x*inv*g.x, v.y*inv*g.y, v.z*inv*g.z, v.w*inv*g.w};
    us4 hv, lv;
    #pragma unroll
    for (int q = 0; q < 4; ++q) {
        unsigned short h = f2bf(f[q]);
        hv[q] = h;
        lv[q] = f2bf(f[q] - bf2f(h));
    }
    unsigned short* rb = outc + (size_t)row * 3072;
    *reinterpret_cast<us4*>(&rb[t*4]) = hv;
    if (ORDER == 0) {
        *reinterpret_cast<us4*>(&rb[1024 + t*4]) = hv;
        *reinterpret_cast<us4*>(&rb[2048 + t*4]) = lv;
    } else {
        *reinterpret_cast<us4*>(&rb[1024 + t*4]) = lv;
        *reinterpret_cast<us4*>(&rb[2048 + t*4]) = hv;
    }
}

// ---------------- softmax stats over fp32 logits ----------------
__global__ void col_stats_partial(const float* __restrict__ logits,
                                  float* __restrict__ pmax, float* __restrict__ psum) {
    int col = blockIdx.x * 256 + threadIdx.x;
    int ch  = blockIdx.y;
    int b   = blockIdx.z;
    const float* base = logits + ((size_t)b * SEQ + (size_t)ch * 512) * ES + col;
    float m = -INFINITY, s = 0.f;
    for (int n = 0; n < 512; ++n) {
        float v = base[(size_t)n * ES];
        float mn = fmaxf(m, v);
        s = s * __expf(m - mn) + __expf(v - mn);
        m = mn;
    }
    size_t idx = ((size_t)b * 8 + ch) * ES + col;
    pmax[idx] = m; psum[idx] = s;
}

__global__ void col_stats_reduce(const float* __restrict__ pmax, const float* __restrict__ psum,
                                 float* __restrict__ cmax, float* __restrict__ cinv) {
    int col = blockIdx.x * 256 + threadIdx.x;
    int b   = blockIdx.y;
    float m = -INFINITY, s = 0.f;
    for (int ch = 0; ch < 8; ++ch) {
        size_t idx = ((size_t)b * 8 + ch) * ES + col;
        float m2 = pmax[idx], s2 = psum[idx];
        float mn = fmaxf(m, m2);
        s = s * __expf(m - mn) + s2 * __expf(m2 - mn);
        m = mn;
    }
    cmax[(size_t)b * ES + col] = m;
    cinv[(size_t)b * ES + col] = 1.0f / s;
}

__global__ void row_stats(const float* __restrict__ logits,
                          float* __restrict__ rmax, float* __restrict__ rinv) {
    int row = blockIdx.x;
    int t = threadIdx.x;
    const float* base = logits + (size_t)row * ES;
    float m = -INFINITY, s = 0.f;
    for (int i = t; i < ES; i += 256) {
        float v = base[i];
        float mn = fmaxf(m, v);
        s = s * __expf(m - mn) + __expf(v - mn);
        m = mn;
    }
    __shared__ float sm[256], ssum[256];
    sm[t] = m; ssum[t] = s;
    __syncthreads();
    for (int off = 128; off >= 1; off >>= 1) {
        if (t < off) {
            float m1 = sm[t], m2 = sm[t+off], s1 = ssum[t], s2 = ssum[t+off];
            float mn = fmaxf(m1, m2);
            sm[t] = mn;
            ssum[t] = s1 * __expf(m1 - mn) + s2 * __expf(m2 - mn);
        }
        __syncthreads();
    }
    if (t == 0) { rmax[row] = sm[0]; rinv[row] = 1.0f / ssum[0]; }
}

// ---------------- fused weights pass ----------------
__global__ void make_weights(const float* __restrict__ logits,
                             const float* __restrict__ cmax, const float* __restrict__ cinv,
                             const float* __restrict__ rmax, const float* __restrict__ rinv,
                             unsigned short* __restrict__ comb, unsigned short* __restrict__ dispT) {
    int b = blockIdx.z;
    const float* L = logits + (size_t)b * SEQ * ES;
    int n0 = blockIdx.y * 32, e0 = blockIdx.x * 32;
    int t = threadIdx.x;
    int r = t >> 3, c4 = (t & 7) * 4;
    __shared__ unsigned short tile[32][36];
    float4 v = *reinterpret_cast<const float4*>(&L[(size_t)(n0 + r) * ES + e0 + c4]);
    float rm = rmax[b*SEQ + n0 + r], ri = rinv[b*SEQ + n0 + r];
    float vv[4] = {v.x, v.y, v.z, v.w};
    us4 cb;
    #pragma unroll
    for (int q = 0; q < 4; ++q) {
        cb[q] = f2bf(__expf(vv[q] - rm) * ri);
        float dv = __expf(vv[q] - cmax[b*ES + e0 + c4 + q]) * cinv[b*ES + e0 + c4 + q];
        tile[c4 + q][r] = f2bf(dv);
    }
    *reinterpret_cast<us4*>(&comb[(size_t)b*SEQ*ES + (size_t)(n0 + r)*ES + e0 + c4]) = cb;
    __syncthreads();
    us4 o = *reinterpret_cast<us4*>(&tile[t >> 3][(t & 7) * 4]);
    *reinterpret_cast<us4*>(&dispT[(size_t)b*ES*SEQ + (size_t)(e0 + (t >> 3))*SEQ + n0 + (t & 7)*4]) = o;
}

// ---------------- bf16 -> bf16 transpose ----------------
__global__ void transpose_b16(const unsigned short* __restrict__ src, unsigned short* __restrict__ dst,
                              int sld, int dld, long sStride, long dStride) {
    int z = blockIdx.z;
    const unsigned short* S = src + (size_t)z * sStride;
    unsigned short* D = dst + (size_t)z * dStride;
    int r0 = blockIdx.y * 32, c0 = blockIdx.x * 32;
    int t = threadIdx.x;
    __shared__ unsigned short tile[32][36];
    us4 v = *reinterpret_cast<const us4*>(&S[(size_t)(r0 + (t>>3)) * sld + c0 + (t&7)*4]);
    #pragma unroll
    for (int q = 0; q < 4; ++q) tile[(t&7)*4 + q][t>>3] = v[q];
    __syncthreads();
    us4 o = *reinterpret_cast<us4*>(&tile[t >> 3][(t & 7) * 4]);
    *reinterpret_cast<us4*>(&D[(size_t)(c0 + (t>>3)) * dld + r0 + (t&7)*4]) = o;
}

// ---------------- f32 -> bf16 transpose ----------------
__global__ void transpose_f32_b16(const float* __restrict__ src, unsigned short* __restrict__ dst,
                                  int sld, int dld, long sStride, long dStride) {
    int z = blockIdx.z;
    const float* S = src + (size_t)z * sStride;
    unsigned short* D = dst + (size_t)z * dStride;
    int r0 = blockIdx.y * 32, c0 = blockIdx.x * 32;
    int t = threadIdx.x;
    __shared__ unsigned short tile[32][36];
    float4 v = *reinterpret_cast<const float4*>(&S[(size_t)(r0 + (t>>3)) * sld + c0 + (t&7)*4]);
    float vv[4] = {v.x, v.y, v.z, v.w};
    #pragma unroll
    for (int q = 0; q < 4; ++q) tile[(t&7)*4 + q][t>>3] = f2bf(vv[q]);
    __syncthreads();
    us4 o = *reinterpret_cast<us4*>(&tile[t >> 3][(t & 7) * 4]);
    *reinterpret_cast<us4*>(&D[(size_t)(c0 + (t>>3)) * dld + r0 + (t&7)*4]) = o;
}

// ================= 256x256 8-phase MFMA GEMM (T1+T2+T3+T4+T5) =================
template<int EPI, int OM>
__global__ __launch_bounds__(512, 2)
void mfma_gemm256(const unsigned short* __restrict__ A, const unsigned short* __restrict__ B,
                  void* __restrict__ Cv, const float* __restrict__ bias,
                  int N, int K, int lda, int ldb, int ldc,
                  long aStride, long bStride, long cStride, int bMod) {
    __shared__ unsigned short lds[65536];   // 128 KB
    const int t = threadIdx.x;
    const int lane = t & 63, wave = t >> 6;
    const int wr = wave >> 2, wc = wave & 3;
    const int z = blockIdx.z, zb = z % bMod;
    const unsigned short* Ab = A + (size_t)z * aStride;
    const unsigned short* Bb = B + (size_t)zb * bStride;
    // T1: bijective XCD swizzle within (x,y) plane (plane % 8 == 0 at all call sites)
    const int gx = gridDim.x;
    int flat = blockIdx.x + blockIdx.y * gx;
    const int cpx = (gx * gridDim.y) >> 3;
    flat = (flat & 7) * cpx + (flat >> 3);
    const int m0 = (flat / gx) * 256, n0 = (flat % gx) * 256;

    const int sr = t >> 3;
    const int sg = (t & 7) ^ (sr & 7);
    const unsigned short* gA = Ab + (size_t)(m0 + sr) * lda + sg * 8;
    const unsigned short* gB = Bb + (size_t)(n0 + sr) * ldb + sg * 8;
    unsigned short* ldsw = lds + wave * 512;

    const int lr = lane & 15, lk = lane >> 4;
    const unsigned sw0 = (unsigned)(((lk)     ^ (lr & 7)) << 4);
    const unsigned sw1 = (unsigned)(((4 + lk) ^ (lr & 7)) << 4);
    const unsigned l0  = ldsoff(lds);
    const unsigned arow = (unsigned)((wr*128 + lr) * 128);
    const unsigned brow = (unsigned)((wc*64  + lr) * 128);
    const unsigned ab00 = l0 + arow + sw0,          ab10 = l0 + arow + sw1;
    const unsigned bb00 = l0 + 32768 + brow + sw0,  bb10 = l0 + 32768 + brow + sw1;
    const unsigned ab01 = ab00 + 65536, ab11 = ab10 + 65536;
    const unsigned bb01 = bb00 + 65536, bb11 = bb10 + 65536;

    #define STAGE_A(buf, half, tt) do { \
        const unsigned short* _g = gA + (size_t)((half)*128) * lda + (tt)*64; \
        unsigned short* _l = ldsw + (buf)*32768 + (half)*8192; \
        GLOAD_LDS16(_g, _l); \
        GLOAD_LDS16(_g + (size_t)64*lda, _l + 4096); } while(0)
    #define STAGE_B(buf, half, tt) do { \
        const unsigned short* _g = gB + (size_t)((half)*128) * ldb + (tt)*64; \
        unsigned short* _l = ldsw + (buf)*32768 + 16384 + (half)*8192; \
        GLOAD_LDS16(_g, _l); \
        GLOAD_LDS16(_g + (size_t)64*ldb, _l + 4096); } while(0)

    f32x4 acc[8][4] = {};
    bf16x8 a0[4], a1[4], b0[4], b1[4];

    const int NT = K / 64;

    STAGE_B(0, 0, 0); STAGE_B(0, 1, 0);
    STAGE_A(0, 0, 0); STAGE_A(0, 1, 0);
    STAGE_B(1, 0, 1); STAGE_B(1, 1, 1);
    asm volatile("s_waitcnt vmcnt(4)" ::: "memory");
    __builtin_amdgcn_s_barrier();

    #define PHASE_MFMA(MB, NB_) \
        __builtin_amdgcn_s_barrier(); \
        asm volatile("s_waitcnt lgkmcnt(0)" ::: "memory"); \
        __builtin_amdgcn_sched_barrier(0); \
        __builtin_amdgcn_s_setprio(1); \
        _Pragma("unroll") \
        for (int m = 0; m < 4; ++m) { \
            _Pragma("unroll") \
            for (int n = 0; n < 2; ++n) { \
                acc[MB+m][NB_+n] = __builtin_amdgcn_mfma_f32_16x16x32_bf16(a0[m], b0[NB_+n], acc[MB+m][NB_+n], 0, 0, 0); \
                acc[MB+m][NB_+n] = __builtin_amdgcn_mfma_f32_16x16x32_bf16(a1[m], b1[NB_+n], acc[MB+m][NB_+n], 0, 0, 0); \
            } \
        } \
        __builtin_amdgcn_s_setprio(0); \
        __builtin_amdgcn_sched_barrier(0); \
        __builtin_amdgcn_s_barrier();

    for (int tt = 0; tt < NT; tt += 2) {
        const bool pf = (tt + 2 < NT);
        DSR(a0[0], ab00, "0");    DSR(a0[1], ab00, "2048");
        DSR(a0[2], ab00, "4096"); DSR(a0[3], ab00, "6144");
        DSR(a1[0], ab10, "0");    DSR(a1[1], ab10, "2048");
        DSR(a1[2], ab10, "4096"); DSR(a1[3], ab10, "6144");
        DSR(b0[0], bb00, "0");    DSR(b0[1], bb00, "2048");
        DSR(b1[0], bb10, "0");    DSR(b1[1], bb10, "2048");
        STAGE_A(1, 0, tt+1);
        __builtin_amdgcn_sched_barrier(0);
        PHASE_MFMA(0, 0)
        DSR(b0[2], bb00, "4096"); DSR(b0[3], bb00, "6144");
        DSR(b1[2], bb10, "4096"); DSR(b1[3], bb10, "6144");
        STAGE_A(1, 1, tt+1);
        __builtin_amdgcn_sched_barrier(0);
        PHASE_MFMA(0, 2)
        DSR(a0[0], ab00, "8192");  DSR(a0[1], ab00, "10240");
        DSR(a0[2], ab00, "12288"); DSR(a0[3], ab00, "14336");
        DSR(a1[0], ab10, "8192");  DSR(a1[1], ab10, "10240");
        DSR(a1[2], ab10, "12288"); DSR(a1[3], ab10, "14336");
        if (pf) STAGE_B(0, 0, tt+2);
        __builtin_amdgcn_sched_barrier(0);
        PHASE_MFMA(4, 0)
        if (pf) STAGE_B(0, 1, tt+2);
        __builtin_amdgcn_sched_barrier(0);
        __builtin_amdgcn_s_barrier();
        __builtin_amdgcn_sched_barrier(0);
        __builtin_amdgcn_s_setprio(1);
        #pragma unroll
        for (int m = 0; m < 4; ++m) {
            #pragma unroll
            for (int n = 0; n < 2; ++n) {
                acc[4+m][2+n] = __builtin_amdgcn_mfma_f32_16x16x32_bf16(a0[m], b0[2+n], acc[4+m][2+n], 0, 0, 0);
                acc[4+m][2+n] = __builtin_amdgcn_mfma_f32_16x16x32_bf16(a1[m], b1[2+n], acc[4+m][2+n], 0, 0, 0);
            }
        }
        __builtin_amdgcn_s_setprio(0);
        if (pf) { asm volatile("s_waitcnt vmcnt(4)" ::: "memory"); }
        else    { asm volatile("s_waitcnt vmcnt(0)" ::: "memory"); }
        __builtin_amdgcn_sched_barrier(0);
        __builtin_amdgcn_s_barrier();
        DSR(a0[0], ab01, "0");    DSR(a0[1], ab01, "2048");
        DSR(a0[2], ab01, "4096"); DSR(a0[3], ab01, "6144");
        DSR(a1[0], ab11, "0");    DSR(a1[1], ab11, "2048");
        DSR(a1[2], ab11, "4096"); DSR(a1[3], ab11, "6144");
        DSR(b0[0], bb01, "0");    DSR(b0[1], bb01, "2048");
        DSR(b1[0], bb11, "0");    DSR(b1[1], bb11, "2048");
        if (pf) STAGE_A(0, 0, tt+2);
        __builtin_amdgcn_sched_barrier(0);
        PHASE_MFMA(0, 0)
        DSR(b0[2], bb01, "4096"); DSR(b0[3], bb01, "6144");
        DSR(b1[2], bb11, "4096"); DSR(b1[3], bb11, "6144");
        if (pf) STAGE_A(0, 1, tt+2);
        __builtin_amdgcn_sched_barrier(0);
        PHASE_MFMA(0, 2)
        DSR(a0[0], ab01, "8192");  DSR(a0[1], ab01, "10240");
        DSR(a0[2], ab01, "12288"); DSR(a0[3], ab01, "14336");
        DSR(a1[0], ab11, "8192");  DSR(a1[1], ab11, "10240");
        DSR(a1[2], ab11, "12288"); DSR(a1[3], ab11, "14336");
        if (pf) STAGE_B(1, 0, tt+3);
        __builtin_amdgcn_sched_barrier(0);
        PHASE_MFMA(4, 0)
        if (pf) STAGE_B(1, 1, tt+3);
        __builtin_amdgcn_sched_barrier(0);
        __builtin_amdgcn_s_barrier();
        __builtin_amdgcn_sched_barrier(0);
        __builtin_amdgcn_s_setprio(1);
        #pragma unroll
        for (int m = 0; m < 4; ++m) {
            #pragma unroll
            for (int n = 0; n < 2; ++n) {
                acc[4+m][2+n] = __builtin_amdgcn_mfma_f32_16x16x32_bf16(a0[m], b0[2+n], acc[4+m][2+n], 0, 0, 0);
                acc[4+m][2+n] = __builtin_amdgcn_mfma_f32_16x16x32_bf16(a1[m], b1[2+n], acc[4+m][2+n], 0, 0, 0);
            }
        }
        __builtin_amdgcn_s_setprio(0);
        if (pf) { asm volatile("s_waitcnt vmcnt(4)" ::: "memory"); }
        else    { asm volatile("s_waitcnt vmcnt(0)" ::: "memory"); }
        __builtin_amdgcn_sched_barrier(0);
        __builtin_amdgcn_s_barrier();
    }

    const float* bz = (EPI != 0) ? bias + (size_t)zb * N : nullptr;
    long coff = (long)z * cStride;
    int rbase = (lane >> 4) * 4;
    int cbase = lane & 15;
    #pragma unroll
    for (int f = 0; f < 8; ++f) {
        #pragma unroll
        for (int n = 0; n < 4; ++n) {
            int col  = n0 + wc*64 + n*16 + cbase;
            int row0 = m0 + wr*128 + f*16 + rbase;
            float bv = (EPI != 0) ? bz[col] : 0.f;
            float vals[4];
            #pragma unroll
            for (int r = 0; r < 4; ++r) {
                float v = acc[f][n][r] + bv;
                if (EPI == 2) v = gelu_exact(v);
                vals[r] = v;
            }
            if (OM == 0) {
                float* C = (float*)Cv + coff;
                #pragma unroll
                for (int r = 0; r < 4; ++r) C[(size_t)(row0 + r) * ldc + col] = vals[r];
            } else {
                unsigned short* C = (unsigned short*)Cv + coff;
                #pragma unroll
                for (int r = 0; r < 4; ++r) C[(size_t)(row0 + r) * ldc + col] = f2bf(vals[r]);
            }
        }
    }
    #undef STAGE_A
    #undef STAGE_B
    #undef PHASE_MFMA
}

// ================= 256x128 4-phase-per-K-tile MFMA GEMM (narrow-N GEMMs) =================
// C[M][N] = A[M][K]*B[N][K]^T. BM=256 BN=128 BK=64, 512 thr (8 waves, 2Mx4N),
// per-wave 128x32 (acc[8][2]). LDS 96KB: buf*24576 elems {A 16384 | B 8192}.
// Per tile t (4 phases): P1 a(m0-3,kk0)+b(kk0), P2 a(kk1)+b(kk1), P3 a(m4-7,kk0), P4 a(kk1).
// Stages: P1/P2 A(t+1)->buf^1, P3 B(t+2)->buf. vmcnt(2) at P4 (vmcnt(0) tail).
template<int EPI, int OM>
__global__ __launch_bounds__(512, 2)
void mfma_gemmX(const unsigned short* __restrict__ A, const unsigned short* __restrict__ B,
                void* __restrict__ Cv, const float* __restrict__ bias,
                int N, int K, int lda, int ldb, int ldc,
                long aStride, long bStride, long cStride, long cStrideE, int bMod) {
    __shared__ unsigned short lds[49152];   // 96 KB
    const int t = threadIdx.x;
    const int lane = t & 63, wave = t >> 6;
    const int wr = wave >> 2, wc = wave & 3;
    const int z = blockIdx.z, zb = z % bMod;
    const unsigned short* Ab = A + (size_t)z * aStride;
    const unsigned short* Bb = B + (size_t)zb * bStride;
    const int gx = gridDim.x;
    int flat = blockIdx.x + blockIdx.y * gx;
    const int cpx = (gx * gridDim.y) >> 3;
    flat = (flat & 7) * cpx + (flat >> 3);
    const int m0 = (flat / gx) * 256, n0 = (flat % gx) * 128;

    const int sr = t >> 3;
    const int sg = (t & 7) ^ (sr & 7);
    const unsigned short* gA = Ab + (size_t)(m0 + sr) * lda + sg * 8;
    const unsigned short* gB = Bb + (size_t)(n0 + sr) * ldb + sg * 8;
    unsigned short* ldsw = lds + wave * 512;

    const int lr = lane & 15, lk = lane >> 4;
    const unsigned g0 = (unsigned)(((lk)     ^ (lr & 7)) << 4);
    const unsigned g1 = (unsigned)(((4 + lk) ^ (lr & 7)) << 4);
    const unsigned l0 = ldsoff(lds);
    const unsigned arow = (unsigned)((wr*128 + lr) * 128);
    const unsigned brow = (unsigned)((wc*32  + lr) * 128);
    const unsigned axk0 = l0 + arow + g0,          axk1 = l0 + arow + g1;
    const unsigned bxk0 = l0 + 32768 + brow + g0,  bxk1 = l0 + 32768 + brow + g1;

    #define STAGE_AX(buf, half, tt) do { \
        const unsigned short* _g = gA + (size_t)((half)*128) * lda + (tt)*64; \
        unsigned short* _l = ldsw + (buf)*24576 + (half)*8192; \
        GLOAD_LDS16(_g, _l); \
        GLOAD_LDS16(_g + (size_t)64*lda, _l + 4096); } while(0)
    #define STAGE_BX(buf, tt) do { \
        const unsigned short* _g = gB + (tt)*64; \
        unsigned short* _l = ldsw + (buf)*24576 + 16384; \
        GLOAD_LDS16(_g, _l); \
        GLOAD_LDS16(_g + (size_t)64*ldb, _l + 4096); } while(0)

    f32x4 acc[8][2] = {};
    bf16x8 a0[4], a1[4], b0[2], b1[2];

    const int NT = K / 64;

    // prologue: B(0),A(0)->buf0; B(1)->buf1; leave B(1) in flight
    STAGE_BX(0, 0);
    STAGE_AX(0, 0, 0); STAGE_AX(0, 1, 0);
    STAGE_BX(1, 1);
    asm volatile("s_waitcnt vmcnt(2)" ::: "memory");
    __builtin_amdgcn_s_barrier();

    #define PHX(MB, AR, BR) \
        __builtin_amdgcn_s_barrier(); \
        asm volatile("s_waitcnt lgkmcnt(0)" ::: "memory"); \
        __builtin_amdgcn_sched_barrier(0); \
        __builtin_amdgcn_s_setprio(1); \
        _Pragma("unroll") \
        for (int m = 0; m < 4; ++m) { \
            _Pragma("unroll") \
            for (int n = 0; n < 2; ++n) { \
                acc[MB+m][n] = __builtin_amdgcn_mfma_f32_16x16x32_bf16(AR[m], BR[n], acc[MB+m][n], 0, 0, 0); \
            } \
        } \
        __builtin_amdgcn_s_setprio(0); \
        __builtin_amdgcn_sched_barrier(0); \
        __builtin_amdgcn_s_barrier();

    #define TILEX(AB0, AB1, BB0, BB1, SBUF, TT) { \
        const bool pf1 = (TT) + 1 < NT, pf2 = (TT) + 2 < NT; \
        /* P1 */ \
        DSR(a0[0], AB0, "0");    DSR(a0[1], AB0, "2048"); \
        DSR(a0[2], AB0, "4096"); DSR(a0[3], AB0, "6144"); \
        DSR(b0[0], BB0, "0");    DSR(b0[1], BB0, "2048"); \
        if (pf1) STAGE_AX((SBUF)^1, 0, (TT)+1); \
        __builtin_amdgcn_sched_barrier(0); \
        PHX(0, a0, b0) \
        /* P2 */ \
        DSR(a1[0], AB1, "0");    DSR(a1[1], AB1, "2048"); \
        DSR(a1[2], AB1, "4096"); DSR(a1[3], AB1, "6144"); \
        DSR(b1[0], BB1, "0");    DSR(b1[1], BB1, "2048"); \
        if (pf1) STAGE_AX((SBUF)^1, 1, (TT)+1); \
        __builtin_amdgcn_sched_barrier(0); \
        PHX(0, a1, b1) \
        /* P3 */ \
        DSR(a0[0], AB0, "8192");  DSR(a0[1], AB0, "10240"); \
        DSR(a0[2], AB0, "12288"); DSR(a0[3], AB0, "14336"); \
        if (pf2) STAGE_BX(SBUF, (TT)+2); \
        __builtin_amdgcn_sched_barrier(0); \
        PHX(4, a0, b0) \
        /* P4 */ \
        DSR(a1[0], AB1, "8192");  DSR(a1[1], AB1, "10240"); \
        DSR(a1[2], AB1, "12288"); DSR(a1[3], AB1, "14336"); \
        __builtin_amdgcn_sched_barrier(0); \
        __builtin_amdgcn_s_barrier(); \
        asm volatile("s_waitcnt lgkmcnt(0)" ::: "memory"); \
        __builtin_amdgcn_sched_barrier(0); \
        __builtin_amdgcn_s_setprio(1); \
        _Pragma("unroll") \
        for (int m = 0; m < 4; ++m) { \
            _Pragma("unroll") \
            for (int n = 0; n < 2; ++n) { \
                acc[4+m][n] = __builtin_amdgcn_mfma_f32_16x16x32_bf16(a1[m], b1[n], acc[4+m][n], 0, 0, 0); \
            } \
        } \
        __builtin_amdgcn_s_setprio(0); \
        if (pf2) { asm volatile("s_waitcnt vmcnt(2)" ::: "memory"); } \
        else     { asm volatile("s_waitcnt vmcnt(0)" ::: "memory"); } \
        __builtin_amdgcn_sched_barrier(0); \
        __builtin_amdgcn_s_barrier(); \
    }

    for (int tt = 0; tt < NT; tt += 2) {
        TILEX(axk0, axk1, bxk0, bxk1, 0, tt)
        TILEX(axk0 + 49152, axk1 + 49152, bxk0 + 49152, bxk1 + 49152, 1, tt + 1)
    }

    const float* bz = (EPI != 0) ? bias + (size_t)zb * N : nullptr;
    long coff = (long)z * cStride + (long)zb * cStrideE;
    int rbase = (lane >> 4) * 4;
    int cbase = lane & 15;
    #pragma unroll
    for (int f = 0; f < 8; ++f) {
        #pragma unroll
        for (int n = 0; n < 2; ++n) {
            int col  = n0 + wc*32 + n*16 + cbase;
            int row0 = m0 + wr*128 + f*16 + rbase;
            float bv = (EPI != 0) ? bz[col] : 0.f;
            float vals[4];
            #pragma unroll
            for (int r = 0; r < 4; ++r) {
                float v = acc[f][n][r] + bv;
                if (EPI == 2) v = gelu_exact(v);
                vals[r] = v;
            }
            if (OM == 0) {
                float* C = (float*)Cv + coff;
                #pragma unroll
                for (int r = 0; r < 4; ++r) C[(size_t)(row0 + r) * ldc + col] = vals[r];
            } else if (OM == 1) {
                unsigned short* C = (unsigned short*)Cv + coff;
                #pragma unroll
                for (int r = 0; r < 4; ++r) C[(size_t)(row0 + r) * ldc + col] = f2bf(vals[r]);
            } else {
                unsigned short* C = (unsigned short*)Cv + coff;
                us4 o;
                #pragma unroll
                for (int r = 0; r < 4; ++r) o[r] = f2bf(vals[r]);
                *reinterpret_cast<us4*>(&C[(size_t)col * ldc + row0]) = o;
            }
        }
    }
    #undef STAGE_AX
    #undef STAGE_BX
    #undef PHX
    #undef TILEX
}

extern "C" void kernel_launch(void* const* d_in, const int* in_sizes, int n_in,
                              void* d_out, int out_size, void* d_ws, size_t ws_size,
                              hipStream_t stream) {
    const float* x    = (const float*)d_in[0];
    const float* ng   = (const float*)d_in[1];
    const float* sg   = (const float*)d_in[2];
    const float* semb = (const float*)d_in[3];
    const float* w1   = (const float*)d_in[4];
    const float* b1   = (const float*)d_in[5];
    const float* w2   = (const float*)d_in[6];
    const float* b2   = (const float*)d_in[7];
    float* out = (float*)d_out;

    // ---- workspace layout with liveness reuse (total ~311 MB) ----
    char* base = (char*)d_ws;
    unsigned short* Acat  = (unsigned short*)(base);               // [8192][3072] bf16 (hi|hi|lo)
    unsigned short* Bcat  = (unsigned short*)(base + 50331648);    // [4096][3072] bf16 (hi|lo|hi)
    unsigned short* dispT = (unsigned short*)(base);               // [2][4096][4096] (reuses Acat+Bcat)
    unsigned short* w2T   = (unsigned short*)(base);               // [8][1024][4096] (reuses dispT)
    float*          logits= (float*)(base + 75497472);             // [2][4096][4096] f32
    unsigned short* hbuf  = (unsigned short*)(base + 75497472);    // [16][512][4096] (reuses logits)
    unsigned short* w1T   = (unsigned short*)(base + 142606336);   // [8][4096][1024] (reuses logits+67MB)
    unsigned short* xnT   = (unsigned short*)(base + 209715200);   // [2][1024][4096]
    unsigned short* comb  = (unsigned short*)(base + 226492416);   // [2][4096][4096]
    unsigned short* slots = (unsigned short*)(base + 293601280);   // [2][4096][1024]
    unsigned short* eoT   = (unsigned short*)(base + 293601280);   // [2][1024][4096] (reuses slots)
    float* pmax = (float*)(base + 310378496);
    float* psum = pmax + 65536;
    float* cmax = psum + 65536;
    float* cinv = cmax + 8192;
    float* rmax = cinv + 8192;
    float* rinv = rmax + 8192;

    // 1. RMSNorm + hi/lo split
    rmsnorm_split<0><<<NB*SEQ, 256, 0, stream>>>(x, ng, Acat);
    rmsnorm_split<1><<<NEXP*NSLOT, 256, 0, stream>>>(semb, sg, Bcat);

    // 2. xnT[b][d][n] = hi(xn) transposed
    transpose_b16<<<dim3(DIM/32, SEQ/32, NB), 256, 0, stream>>>(
        Acat, xnT, 3072, SEQ, (long)SEQ*3072, (long)DIM*SEQ);

    // 3. logits = [x_hi|x_hi|x_lo] @ [s_hi|s_lo|s_hi]^T  (K=3072) — 8-phase 256² + T1
    mfma_gemm256<0,0><<<dim3(ES/256, (NB*SEQ)/256, 1), 512, 0, stream>>>(
        Acat, Bcat, logits, nullptr, ES, 3072, 3072, 3072, ES,
        0L, 0L, 0L, 1);

    // 4. softmax stats
    col_stats_partial<<<dim3(ES/256, 8, NB), 256, 0, stream>>>(logits, pmax, psum);
    col_stats_reduce<<<dim3(ES/256, NB), 256, 0, stream>>>(pmax, psum, cmax, cinv);
    row_stats<<<NB*SEQ, 256, 0, stream>>>(logits, rmax, rinv);

    // 5. comb + dispT (bf16). Acat/Bcat dead.
    make_weights<<<dim3(ES/32, SEQ/32, NB), 256, 0, stream>>>(
        logits, cmax, cinv, rmax, rinv, comb, dispT);

    // 6. w1T[e][hid][dim] (logits dead)
    transpose_f32_b16<<<dim3(HID/32, DIM/32, NEXP), 256, 0, stream>>>(
        w1, w1T, HID, DIM, (long)DIM*HID, (long)HID*DIM);

    // 7. slots = dispT @ xnT^T   M=4096 N=1024 K=4096 — 256x128 4-phase
    mfma_gemmX<0,1><<<dim3(DIM/128, ES/256, NB), 512, 0, stream>>>(
        dispT, xnT, slots, nullptr, DIM, SEQ, SEQ, SEQ, DIM,
        (long)ES*SEQ, (long)DIM*SEQ, (long)ES*DIM, 0L, NB);

    // 8. w2T[e][dim][hid] (dispT dead)
    transpose_f32_b16<<<dim3(DIM/32, HID/32, NEXP), 256, 0, stream>>>(
        w2, w2T, DIM, HID, (long)HID*DIM, (long)DIM*HID);

    // 9. FF1: h = gelu(slots @ w1T^T + b1)  M=512 N=4096 K=1024 — 8-phase 256² + T1
    mfma_gemm256<2,1><<<dim3(HID/256, NSLOT/256, NB*NEXP), 512, 0, stream>>>(
        slots, w1T, hbuf, b1, HID, DIM, DIM, DIM, HID,
        (long)NSLOT*DIM, (long)HID*DIM, (long)NSLOT*HID, NEXP);

    // 10. FF2: eoT = (h @ w2T^T + b2)^T  M=512 N=1024 K=4096 — 256x128 4-phase
    mfma_gemmX<1,2><<<dim3(DIM/128, NSLOT/256, NB*NEXP), 512, 0, stream>>>(
        hbuf, w2T, eoT, b2, DIM, HID, HID, HID, ES,
        (long)NSLOT*HID, (long)DIM*HID, (long)(DIM*ES/NEXP), (long)(NSLOT - DIM*ES/NEXP), NEXP);

    // 11. out = comb @ eoT^T   M=4096 N=1024 K=4096 — 256x128 4-phase
    mfma_gemmX<0,0><<<dim3(DIM/128, SEQ/256, NB), 512, 0, stream>>>(
        comb, eoT, out, nullptr, DIM, ES, ES, ES, DIM,
        (long)SEQ*ES, (long)DIM*ES, (long)SEQ*DIM, 0L, NB);
}

// Round 5
// 707.930 us; speedup vs baseline: 6.4945x; 1.0173x over previous
//
#include <hip/hip_runtime.h>
#include <math.h>

#define SEQ    4096
#define DIM    1024
#define NEXP   8
#define NSLOT  512
#define ES     4096
#define HID    4096
#define NB     2
#define RMS_SCALE 32.0f

typedef __attribute__((ext_vector_type(4))) float f32x4;
typedef __attribute__((ext_vector_type(8))) short bf16x8;
typedef __attribute__((ext_vector_type(4))) unsigned short us4;

__device__ __forceinline__ unsigned short f2bf(float f) {
    unsigned u = __float_as_uint(f);
    u += 0x7fff + ((u >> 16) & 1);          // round-to-nearest-even
    return (unsigned short)(u >> 16);
}
__device__ __forceinline__ float bf2f(unsigned short h) {
    return __uint_as_float(((unsigned)h) << 16);
}
__device__ __forceinline__ float gelu_exact(float x) {
    return 0.5f * x * (1.0f + erff(x * 0.70710678118654752f));
}

#define GLOAD_LDS16(gp, lp) \
    __builtin_amdgcn_global_load_lds((const __attribute__((address_space(1))) void*)(gp), \
                                     (__attribute__((address_space(3))) void*)(lp), 16, 0, 0)

__device__ __forceinline__ unsigned ldsoff(const void* p) {
    return (unsigned)(size_t)(const __attribute__((address_space(3))) void*)p;
}

#define DSR(dst, base, off) asm volatile("ds_read_b128 %0, %1 offset:" off : "=v"(dst) : "v"(base))
#define VM(n) asm volatile("s_waitcnt vmcnt(" #n ")" ::: "memory")
#define BAR __builtin_amdgcn_s_barrier()
#define SCB __builtin_amdgcn_sched_barrier(0)

#define PH_OPEN  SCB; BAR; asm volatile("s_waitcnt lgkmcnt(0)" ::: "memory"); SCB; \
                 __builtin_amdgcn_s_setprio(1);
#define PH_CLOSE __builtin_amdgcn_s_setprio(0); SCB;

// ---------------- RMSNorm + bf16 hi/lo split into K-concat layout ----------------
template<int ORDER>
__global__ void rmsnorm_split(const float* __restrict__ in, const float* __restrict__ gamma,
                              unsigned short* __restrict__ outc) {
    int row = blockIdx.x;
    int t = threadIdx.x;
    float4 v = reinterpret_cast<const float4*>(in + (size_t)row * DIM)[t];
    float ss = v.x*v.x + v.y*v.y + v.z*v.z + v.w*v.w;
    #pragma unroll
    for (int off = 32; off >= 1; off >>= 1) ss += __shfl_down(ss, off, 64);
    __shared__ float red[4];
    if ((t & 63) == 0) red[t >> 6] = ss;
    __syncthreads();
    float inv = RMS_SCALE / fmaxf(sqrtf(red[0] + red[1] + red[2] + red[3]), 1e-12f);
    float4 g = reinterpret_cast<const float4*>(gamma)[t];
    float f[4] = {v.x*inv*g.x, v.y*inv*g.y, v.z*inv*g.z, v.w*inv*g.w};
    us4 hv, lv;
    #pragma unroll
    for (int q = 0; q < 4; ++q) {
        unsigned short h = f2bf(f[q]);
        hv[q] = h;
        lv[q] = f2bf(f[q] - bf2f(h));
    }
    unsigned short* rb = outc + (size_t)row * 3072;
    *reinterpret_cast<us4*>(&rb[t*4]) = hv;
    if (ORDER == 0) {
        *reinterpret_cast<us4*>(&rb[1024 + t*4]) = hv;
        *reinterpret_cast<us4*>(&rb[2048 + t*4]) = lv;
    } else {
        *reinterpret_cast<us4*>(&rb[1024 + t*4]) = lv;
        *reinterpret_cast<us4*>(&rb[2048 + t*4]) = hv;
    }
}

// ---------------- softmax stats over fp32 logits ----------------
__global__ void col_stats_partial(const float* __restrict__ logits,
                                  float* __restrict__ pmax, float* __restrict__ psum) {
    int col = blockIdx.x * 256 + threadIdx.x;
    int ch  = blockIdx.y;
    int b   = blockIdx.z;
    const float* base = logits + ((size_t)b * SEQ + (size_t)ch * 512) * ES + col;
    float m = -INFINITY, s = 0.f;
    for (int n = 0; n < 512; ++n) {
        float v = base[(size_t)n * ES];
        float mn = fmaxf(m, v);
        s = s * __expf(m - mn) + __expf(v - mn);
        m = mn;
    }
    size_t idx = ((size_t)b * 8 + ch) * ES + col;
    pmax[idx] = m; psum[idx] = s;
}

__global__ void col_stats_reduce(const float* __restrict__ pmax, const float* __restrict__ psum,
                                 float* __restrict__ cmax, float* __restrict__ cinv) {
    int col = blockIdx.x * 256 + threadIdx.x;
    int b   = blockIdx.y;
    float m = -INFINITY, s = 0.f;
    for (int ch = 0; ch < 8; ++ch) {
        size_t idx = ((size_t)b * 8 + ch) * ES + col;
        float m2 = pmax[idx], s2 = psum[idx];
        float mn = fmaxf(m, m2);
        s = s * __expf(m - mn) + s2 * __expf(m2 - mn);
        m = mn;
    }
    cmax[(size_t)b * ES + col] = m;
    cinv[(size_t)b * ES + col] = 1.0f / s;
}

__global__ void row_stats(const float* __restrict__ logits,
                          float* __restrict__ rmax, float* __restrict__ rinv) {
    int row = blockIdx.x;
    int t = threadIdx.x;
    const float* base = logits + (size_t)row * ES;
    float m = -INFINITY, s = 0.f;
    for (int i = t; i < ES; i += 256) {
        float v = base[i];
        float mn = fmaxf(m, v);
        s = s * __expf(m - mn) + __expf(v - mn);
        m = mn;
    }
    __shared__ float sm[256], ssum[256];
    sm[t] = m; ssum[t] = s;
    __syncthreads();
    for (int off = 128; off >= 1; off >>= 1) {
        if (t < off) {
            float m1 = sm[t], m2 = sm[t+off], s1 = ssum[t], s2 = ssum[t+off];
            float mn = fmaxf(m1, m2);
            sm[t] = mn;
            ssum[t] = s1 * __expf(m1 - mn) + s2 * __expf(m2 - mn);
        }
        __syncthreads();
    }
    if (t == 0) { rmax[row] = sm[0]; rinv[row] = 1.0f / ssum[0]; }
}

// ---------------- fused weights pass ----------------
__global__ void make_weights(const float* __restrict__ logits,
                             const float* __restrict__ cmax, const float* __restrict__ cinv,
                             const float* __restrict__ rmax, const float* __restrict__ rinv,
                             unsigned short* __restrict__ comb, unsigned short* __restrict__ dispT) {
    int b = blockIdx.z;
    const float* L = logits + (size_t)b * SEQ * ES;
    int n0 = blockIdx.y * 32, e0 = blockIdx.x * 32;
    int t = threadIdx.x;
    int r = t >> 3, c4 = (t & 7) * 4;
    __shared__ unsigned short tile[32][36];
    float4 v = *reinterpret_cast<const float4*>(&L[(size_t)(n0 + r) * ES + e0 + c4]);
    float rm = rmax[b*SEQ + n0 + r], ri = rinv[b*SEQ + n0 + r];
    float vv[4] = {v.x, v.y, v.z, v.w};
    us4 cb;
    #pragma unroll
    for (int q = 0; q < 4; ++q) {
        cb[q] = f2bf(__expf(vv[q] - rm) * ri);
        float dv = __expf(vv[q] - cmax[b*ES + e0 + c4 + q]) * cinv[b*ES + e0 + c4 + q];
        tile[c4 + q][r] = f2bf(dv);
    }
    *reinterpret_cast<us4*>(&comb[(size_t)b*SEQ*ES + (size_t)(n0 + r)*ES + e0 + c4]) = cb;
    __syncthreads();
    us4 o = *reinterpret_cast<us4*>(&tile[t >> 3][(t & 7) * 4]);
    *reinterpret_cast<us4*>(&dispT[(size_t)b*ES*SEQ + (size_t)(e0 + (t >> 3))*SEQ + n0 + (t & 7)*4]) = o;
}

// ---------------- bf16 -> bf16 transpose ----------------
__global__ void transpose_b16(const unsigned short* __restrict__ src, unsigned short* __restrict__ dst,
                              int sld, int dld, long sStride, long dStride) {
    int z = blockIdx.z;
    const unsigned short* S = src + (size_t)z * sStride;
    unsigned short* D = dst + (size_t)z * dStride;
    int r0 = blockIdx.y * 32, c0 = blockIdx.x * 32;
    int t = threadIdx.x;
    __shared__ unsigned short tile[32][36];
    us4 v = *reinterpret_cast<const us4*>(&S[(size_t)(r0 + (t>>3)) * sld + c0 + (t&7)*4]);
    #pragma unroll
    for (int q = 0; q < 4; ++q) tile[(t&7)*4 + q][t>>3] = v[q];
    __syncthreads();
    us4 o = *reinterpret_cast<us4*>(&tile[t >> 3][(t & 7) * 4]);
    *reinterpret_cast<us4*>(&D[(size_t)(c0 + (t>>3)) * dld + r0 + (t&7)*4]) = o;
}

// ---------------- f32 -> bf16 transpose ----------------
__global__ void transpose_f32_b16(const float* __restrict__ src, unsigned short* __restrict__ dst,
                                  int sld, int dld, long sStride, long dStride) {
    int z = blockIdx.z;
    const float* S = src + (size_t)z * sStride;
    unsigned short* D = dst + (size_t)z * dStride;
    int r0 = blockIdx.y * 32, c0 = blockIdx.x * 32;
    int t = threadIdx.x;
    __shared__ unsigned short tile[32][36];
    float4 v = *reinterpret_cast<const float4*>(&S[(size_t)(r0 + (t>>3)) * sld + c0 + (t&7)*4]);
    float vv[4] = {v.x, v.y, v.z, v.w};
    #pragma unroll
    for (int q = 0; q < 4; ++q) tile[(t&7)*4 + q][t>>3] = f2bf(vv[q]);
    __syncthreads();
    us4 o = *reinterpret_cast<us4*>(&tile[t >> 3][(t & 7) * 4]);
    *reinterpret_cast<us4*>(&D[(size_t)(c0 + (t>>3)) * dld + r0 + (t&7)*4]) = o;
}

// ================= 256x256 8-phase deep-prefetch MFMA GEMM =================
// Quadrant-aligned LDS halves: A h0 = rows {0-63}U{128-191}, h1 = {64-127}U{192-255};
// B h0 = rows {c*64+0..31}, h1 = {c*64+32..63}. Staged one-iteration (8 phases) ahead;
// uniform vmcnt(10) (5 half-tiles in flight), tail descending 8/4/2/0.
template<int EPI, int OM>
__global__ __launch_bounds__(512, 2)
void mfma_gemm256(const unsigned short* __restrict__ A, const unsigned short* __restrict__ B,
                  void* __restrict__ Cv, const float* __restrict__ bias,
                  int N, int K, int lda, int ldb, int ldc,
                  long aStride, long bStride, long cStride, int bMod) {
    __shared__ unsigned short lds[65536];   // 128 KB
    const int t = threadIdx.x;
    const int lane = t & 63, wave = t >> 6;
    const int wr = wave >> 2, wc = wave & 3;
    const int z = blockIdx.z, zb = z % bMod;
    const unsigned short* Ab = A + (size_t)z * aStride;
    const unsigned short* Bb = B + (size_t)zb * bStride;
    const int gx = gridDim.x;
    int flat = blockIdx.x + blockIdx.y * gx;
    const int cpx = (gx * gridDim.y) >> 3;
    flat = (flat & 7) * cpx + (flat >> 3);
    const int m0 = (flat / gx) * 256, n0 = (flat % gx) * 256;

    const int sr = t >> 3;                    // slot-row within an 8KB load
    const int sg = (t & 7) ^ (sr & 7);        // pre-swizzled 16B group
    const unsigned short* gA = Ab + (size_t)(m0 + sr) * lda + sg * 8;
    const int srB = sr + (sr & 32);           // B quad row map (slot -> global row)
    const unsigned short* gB = Bb + (size_t)(n0 + srB) * ldb + sg * 8;
    unsigned short* ldsw = lds + wave * 512;

    const int lr = lane & 15, lk = lane >> 4;
    const unsigned sw0 = (unsigned)(((lk)     ^ (lr & 7)) << 4);
    const unsigned sw1 = (unsigned)(((4 + lk) ^ (lr & 7)) << 4);
    const unsigned l0  = ldsoff(lds);
    const unsigned arow = (unsigned)((wr*64 + lr) * 128);   // slot-row of A quad frags
    const unsigned brow = (unsigned)((wc*32 + lr) * 128);   // slot-row of B quad frags
    const unsigned ab00 = l0 + arow + sw0,          ab10 = l0 + arow + sw1;
    const unsigned bb00 = l0 + 32768 + brow + sw0,  bb10 = l0 + 32768 + brow + sw1;
    const unsigned ab01 = ab00 + 65536, ab11 = ab10 + 65536;
    const unsigned bb01 = bb00 + 65536, bb11 = bb10 + 65536;

    // A: h0 -> global rows {0-63}(L1),{128-191}(L2); h1 -> {64-127},{192-255}
    #define STAGE_A(buf, half, tt) do { \
        const unsigned short* _g = gA + (size_t)((half)*64) * lda + (tt)*64; \
        unsigned short* _l = ldsw + (buf)*32768 + (half)*8192; \
        GLOAD_LDS16(_g, _l); \
        GLOAD_LDS16(_g + (size_t)128*lda, _l + 4096); } while(0)
    // B: h0 -> rows {srB}(L1),{srB+128}(L2); h1 -> +32
    #define STAGE_B(buf, half, tt) do { \
        const unsigned short* _g = gB + (size_t)((half)*32) * ldb + (tt)*64; \
        unsigned short* _l = ldsw + (buf)*32768 + 16384 + (half)*8192; \
        GLOAD_LDS16(_g, _l); \
        GLOAD_LDS16(_g + (size_t)128*ldb, _l + 4096); } while(0)

    #define MFMA16(MB, CN) \
        _Pragma("unroll") \
        for (int m = 0; m < 4; ++m) { \
            _Pragma("unroll") \
            for (int n = 0; n < 2; ++n) { \
                acc[(MB)+m][(CN)+n] = __builtin_amdgcn_mfma_f32_16x16x32_bf16(a0[m], b0[(CN)+n], acc[(MB)+m][(CN)+n], 0, 0, 0); \
                acc[(MB)+m][(CN)+n] = __builtin_amdgcn_mfma_f32_16x16x32_bf16(a1[m], b1[(CN)+n], acc[(MB)+m][(CN)+n], 0, 0, 0); \
            } \
        }

    f32x4 acc[8][4] = {};
    bf16x8 a0[4], a1[4], b0[4], b1[4];
    const int NT = K / 64;

    // prologue: sigma2..sigma8 in steady-state issue order
    STAGE_A(0, 0, 0); STAGE_B(0, 0, 0); STAGE_B(0, 1, 0); STAGE_A(0, 1, 0);
    STAGE_A(1, 0, 1); STAGE_B(1, 0, 1); STAGE_B(1, 1, 1);
    VM(10); BAR;

    for (int tt = 0; tt < NT; tt += 2) {
        const bool pf2 = (tt + 2 < NT);
        const bool pf3 = (tt + 3 < NT);
        // ---- P1: read Ah0(t)+Bh0(t) [buf0]; stage Ah1(t+1)->buf1 (s1)
        DSR(a0[0], ab00, "0");    DSR(a0[1], ab00, "2048");
        DSR(a0[2], ab00, "4096"); DSR(a0[3], ab00, "6144");
        DSR(a1[0], ab10, "0");    DSR(a1[1], ab10, "2048");
        DSR(a1[2], ab10, "4096"); DSR(a1[3], ab10, "6144");
        DSR(b0[0], bb00, "0");    DSR(b0[1], bb00, "2048");
        DSR(b1[0], bb10, "0");    DSR(b1[1], bb10, "2048");
        STAGE_A(1, 1, tt+1);
        PH_OPEN MFMA16(0, 0) PH_CLOSE
        VM(10); BAR;
        // ---- P2: read Bh1(t); stage Ah0(t+2)->buf0 (s2)
        DSR(b0[2], bb00, "16384"); DSR(b0[3], bb00, "18432");
        DSR(b1[2], bb10, "16384"); DSR(b1[3], bb10, "18432");
        if (pf2) STAGE_A(0, 0, tt+2);
        PH_OPEN MFMA16(0, 2) PH_CLOSE
        if (pf2) { VM(10); } else { VM(8); }
        BAR;
        // ---- P3: read Ah1(t); stage Bh0(t+2)->buf0 (s3)
        DSR(a0[0], ab00, "16384"); DSR(a0[1], ab00, "18432");
        DSR(a0[2], ab00, "20480"); DSR(a0[3], ab00, "22528");
        DSR(a1[0], ab10, "16384"); DSR(a1[1], ab10, "18432");
        DSR(a1[2], ab10, "20480"); DSR(a1[3], ab10, "22528");
        if (pf2) STAGE_B(0, 0, tt+2);
        PH_OPEN MFMA16(4, 0) PH_CLOSE
        BAR;
        // ---- P4: no reads; stage Bh1(t+2)->buf0 (s4)
        if (pf2) STAGE_B(0, 1, tt+2);
        PH_OPEN MFMA16(4, 2) PH_CLOSE
        if (pf2) { VM(10); } else { VM(4); }
        BAR;
        // ---- P5: read Ah0(t+1)+Bh0(t+1) [buf1]; stage Ah1(t+2)->buf0 (s5)
        DSR(a0[0], ab01, "0");    DSR(a0[1], ab01, "2048");
        DSR(a0[2], ab01, "4096"); DSR(a0[3], ab01, "6144");
        DSR(a1[0], ab11, "0");    DSR(a1[1], ab11, "2048");
        DSR(a1[2], ab11, "4096"); DSR(a1[3], ab11, "6144");
        DSR(b0[0], bb01, "0");    DSR(b0[1], bb01, "2048");
        DSR(b1[0], bb11, "0");    DSR(b1[1], bb11, "2048");
        if (pf2) STAGE_A(0, 1, tt+2);
        PH_OPEN MFMA16(0, 0) PH_CLOSE
        if (pf2) { VM(10); } else { VM(2); }
        BAR;
        // ---- P6: read Bh1(t+1); stage Ah0(t+3)->buf1 (s6)
        DSR(b0[2], bb01, "16384"); DSR(b0[3], bb01, "18432");
        DSR(b1[2], bb11, "16384"); DSR(b1[3], bb11, "18432");
        if (pf3) STAGE_A(1, 0, tt+3);
        PH_OPEN MFMA16(0, 2) PH_CLOSE
        if (pf2) { VM(10); } else { VM(0); }
        BAR;
        // ---- P7: read Ah1(t+1); stage Bh0(t+3)->buf1 (s7)
        DSR(a0[0], ab01, "16384"); DSR(a0[1], ab01, "18432");
        DSR(a0[2], ab01, "20480"); DSR(a0[3], ab01, "22528");
        DSR(a1[0], ab11, "16384"); DSR(a1[1], ab11, "18432");
        DSR(a1[2], ab11, "20480"); DSR(a1[3], ab11, "22528");
        if (pf3) STAGE_B(1, 0, tt+3);
        PH_OPEN MFMA16(4, 0) PH_CLOSE
        BAR;
        // ---- P8: no reads; stage Bh1(t+3)->buf1 (s8)
        if (pf3) STAGE_B(1, 1, tt+3);
        PH_OPEN MFMA16(4, 2) PH_CLOSE
        if (pf2) { VM(10); } else { VM(0); }
        BAR;
    }

    const float* bz = (EPI != 0) ? bias + (size_t)zb * N : nullptr;
    long coff = (long)z * cStride;
    int rbase = (lane >> 4) * 4;
    int cbase = lane & 15;
    #pragma unroll
    for (int f = 0; f < 8; ++f) {
        #pragma unroll
        for (int n = 0; n < 4; ++n) {
            int col  = n0 + wc*64 + n*16 + cbase;
            int row0 = m0 + wr*128 + f*16 + rbase;
            float bv = (EPI != 0) ? bz[col] : 0.f;
            float vals[4];
            #pragma unroll
            for (int r = 0; r < 4; ++r) {
                float v = acc[f][n][r] + bv;
                if (EPI == 2) v = gelu_exact(v);
                vals[r] = v;
            }
            if (OM == 0) {
                float* C = (float*)Cv + coff;
                #pragma unroll
                for (int r = 0; r < 4; ++r) C[(size_t)(row0 + r) * ldc + col] = vals[r];
            } else {
                unsigned short* C = (unsigned short*)Cv + coff;
                #pragma unroll
                for (int r = 0; r < 4; ++r) C[(size_t)(row0 + r) * ldc + col] = f2bf(vals[r]);
            }
        }
    }
    #undef STAGE_A
    #undef STAGE_B
    #undef MFMA16
}

// ================= 256x128 8-phase deep-prefetch MFMA GEMM (narrow-N) =================
// A quad halves as above; B (128 rows) plain. Stages: P1:Aq1(t+1)->b1, P3:Aq0(t+2)->b0,
// P4:B(t+2)->b0, P5:Aq1(t+2)->b0, P7:Aq0(t+3)->b1, P8:B(t+3)->b1. vmcnt(6) at P2/P4/P6/P8
// (tail 6/2/0/0).
template<int EPI, int OM>
__global__ __launch_bounds__(512, 2)
void mfma_gemmX(const unsigned short* __restrict__ A, const unsigned short* __restrict__ B,
                void* __restrict__ Cv, const float* __restrict__ bias,
                int N, int K, int lda, int ldb, int ldc,
                long aStride, long bStride, long cStride, long cStrideE, int bMod) {
    __shared__ unsigned short lds[49152];   // 96 KB
    const int t = threadIdx.x;
    const int lane = t & 63, wave = t >> 6;
    const int wr = wave >> 2, wc = wave & 3;
    const int z = blockIdx.z, zb = z % bMod;
    const unsigned short* Ab = A + (size_t)z * aStride;
    const unsigned short* Bb = B + (size_t)zb * bStride;
    const int gx = gridDim.x;
    int flat = blockIdx.x + blockIdx.y * gx;
    const int cpx = (gx * gridDim.y) >> 3;
    flat = (flat & 7) * cpx + (flat >> 3);
    const int m0 = (flat / gx) * 256, n0 = (flat % gx) * 128;

    const int sr = t >> 3;
    const int sg = (t & 7) ^ (sr & 7);
    const unsigned short* gA = Ab + (size_t)(m0 + sr) * lda + sg * 8;
    const unsigned short* gB = Bb + (size_t)(n0 + sr) * ldb + sg * 8;
    unsigned short* ldsw = lds + wave * 512;

    const int lr = lane & 15, lk = lane >> 4;
    const unsigned g0 = (unsigned)(((lk)     ^ (lr & 7)) << 4);
    const unsigned g1 = (unsigned)(((4 + lk) ^ (lr & 7)) << 4);
    const unsigned l0 = ldsoff(lds);
    const unsigned arow = (unsigned)((wr*64 + lr) * 128);
    const unsigned brow = (unsigned)((wc*32 + lr) * 128);
    const unsigned ax00 = l0 + arow + g0,          ax10 = l0 + arow + g1;
    const unsigned bx00 = l0 + 32768 + brow + g0,  bx10 = l0 + 32768 + brow + g1;
    const unsigned ax01 = ax00 + 49152, ax11 = ax10 + 49152;
    const unsigned bx01 = bx00 + 49152, bx11 = bx10 + 49152;

    #define STAGE_AX(buf, quad, tt) do { \
        const unsigned short* _g = gA + (size_t)((quad)*64) * lda + (tt)*64; \
        unsigned short* _l = ldsw + (buf)*24576 + (quad)*8192; \
        GLOAD_LDS16(_g, _l); \
        GLOAD_LDS16(_g + (size_t)128*lda, _l + 4096); } while(0)
    #define STAGE_BX(buf, tt) do { \
        const unsigned short* _g = gB + (tt)*64; \
        unsigned short* _l = ldsw + (buf)*24576 + 16384; \
        GLOAD_LDS16(_g, _l); \
        GLOAD_LDS16(_g + (size_t)64*ldb, _l + 4096); } while(0)

    #define MFMA8(MB, AR, BR) \
        _Pragma("unroll") \
        for (int m = 0; m < 4; ++m) { \
            _Pragma("unroll") \
            for (int n = 0; n < 2; ++n) { \
                acc[(MB)+m][n] = __builtin_amdgcn_mfma_f32_16x16x32_bf16(AR[m], BR[n], acc[(MB)+m][n], 0, 0, 0); \
            } \
        }

    f32x4 acc[8][2] = {};
    bf16x8 a0[4], a1[4], b0[2], b1[2];
    const int NT = K / 64;

    // prologue: s2..s6 in issue order
    STAGE_AX(0, 0, 0); STAGE_BX(0, 0); STAGE_AX(0, 1, 0);
    STAGE_AX(1, 0, 1); STAGE_BX(1, 1);
    VM(6); BAR;

    for (int tt = 0; tt < NT; tt += 2) {
        const bool pf2 = (tt + 2 < NT);
        const bool pf3 = (tt + 3 < NT);
        // ---- P1: Aq0(t) kk0 + B(t) kk0 [buf0]; stage Aq1(t+1)->buf1 (s1)
        DSR(a0[0], ax00, "0");    DSR(a0[1], ax00, "2048");
        DSR(a0[2], ax00, "4096"); DSR(a0[3], ax00, "6144");
        DSR(b0[0], bx00, "0");    DSR(b0[1], bx00, "2048");
        STAGE_AX(1, 1, tt+1);
        PH_OPEN MFMA8(0, a0, b0) PH_CLOSE
        BAR;
        // ---- P2: kk1
        DSR(a1[0], ax10, "0");    DSR(a1[1], ax10, "2048");
        DSR(a1[2], ax10, "4096"); DSR(a1[3], ax10, "6144");
        DSR(b1[0], bx10, "0");    DSR(b1[1], bx10, "2048");
        PH_OPEN MFMA8(0, a1, b1) PH_CLOSE
        VM(6); BAR;
        // ---- P3: Aq1(t) kk0; stage Aq0(t+2)->buf0 (s2)
        DSR(a0[0], ax00, "16384"); DSR(a0[1], ax00, "18432");
        DSR(a0[2], ax00, "20480"); DSR(a0[3], ax00, "22528");
        if (pf2) STAGE_AX(0, 0, tt+2);
        PH_OPEN MFMA8(4, a0, b0) PH_CLOSE
        BAR;
        // ---- P4: Aq1(t) kk1; stage B(t+2)->buf0 (s3)
        DSR(a1[0], ax10, "16384"); DSR(a1[1], ax10, "18432");
        DSR(a1[2], ax10, "20480"); DSR(a1[3], ax10, "22528");
        if (pf2) STAGE_BX(0, tt+2);
        PH_OPEN MFMA8(4, a1, b1) PH_CLOSE
        if (pf2) { VM(6); } else { VM(2); }
        BAR;
        // ---- P5: Aq0(t+1) kk0 + B(t+1) kk0 [buf1]; stage Aq1(t+2)->buf0 (s4)
        DSR(a0[0], ax01, "0");    DSR(a0[1], ax01, "2048");
        DSR(a0[2], ax01, "4096"); DSR(a0[3], ax01, "6144");
        DSR(b0[0], bx01, "0");    DSR(b0[1], bx01, "2048");
        if (pf2) STAGE_AX(0, 1, tt+2);
        PH_OPEN MFMA8(0, a0, b0) PH_CLOSE
        BAR;
        // ---- P6: kk1
        DSR(a1[0], ax11, "0");    DSR(a1[1], ax11, "2048");
        DSR(a1[2], ax11, "4096"); DSR(a1[3], ax11, "6144");
        DSR(b1[0], bx11, "0");    DSR(b1[1], bx11, "2048");
        PH_OPEN MFMA8(0, a1, b1) PH_CLOSE
        if (pf2) { VM(6); } else { VM(0); }
        BAR;
        // ---- P7: Aq1(t+1) kk0; stage Aq0(t+3)->buf1 (s5)
        DSR(a0[0], ax01, "16384"); DSR(a0[1], ax01, "18432");
        DSR(a0[2], ax01, "20480"); DSR(a0[3], ax01, "22528");
        if (pf3) STAGE_AX(1, 0, tt+3);
        PH_OPEN MFMA8(4, a0, b0) PH_CLOSE
        BAR;
        // ---- P8: Aq1(t+1) kk1; stage B(t+3)->buf1 (s6)
        DSR(a1[0], ax11, "16384"); DSR(a1[1], ax11, "18432");
        DSR(a1[2], ax11, "20480"); DSR(a1[3], ax11, "22528");
        if (pf3) STAGE_BX(1, tt+3);
        PH_OPEN MFMA8(4, a1, b1) PH_CLOSE
        if (pf2) { VM(6); } else { VM(0); }
        BAR;
    }

    const float* bz = (EPI != 0) ? bias + (size_t)zb * N : nullptr;
    long coff = (long)z * cStride + (long)zb * cStrideE;
    int rbase = (lane >> 4) * 4;
    int cbase = lane & 15;
    #pragma unroll
    for (int f = 0; f < 8; ++f) {
        #pragma unroll
        for (int n = 0; n < 2; ++n) {
            int col  = n0 + wc*32 + n*16 + cbase;
            int row0 = m0 + wr*128 + f*16 + rbase;
            float bv = (EPI != 0) ? bz[col] : 0.f;
            float vals[4];
            #pragma unroll
            for (int r = 0; r < 4; ++r) {
                float v = acc[f][n][r] + bv;
                if (EPI == 2) v = gelu_exact(v);
                vals[r] = v;
            }
            if (OM == 0) {
                float* C = (float*)Cv + coff;
                #pragma unroll
                for (int r = 0; r < 4; ++r) C[(size_t)(row0 + r) * ldc + col] = vals[r];
            } else if (OM == 1) {
                unsigned short* C = (unsigned short*)Cv + coff;
                #pragma unroll
                for (int r = 0; r < 4; ++r) C[(size_t)(row0 + r) * ldc + col] = f2bf(vals[r]);
            } else {
                unsigned short* C = (unsigned short*)Cv + coff;
                us4 o;
                #pragma unroll
                for (int r = 0; r < 4; ++r) o[r] = f2bf(vals[r]);
                *reinterpret_cast<us4*>(&C[(size_t)col * ldc + row0]) = o;
            }
        }
    }
    #undef STAGE_AX
    #undef STAGE_BX
    #undef MFMA8
}

extern "C" void kernel_launch(void* const* d_in, const int* in_sizes, int n_in,
                              void* d_out, int out_size, void* d_ws, size_t ws_size,
                              hipStream_t stream) {
    const float* x    = (const float*)d_in[0];
    const float* ng   = (const float*)d_in[1];
    const float* sg   = (const float*)d_in[2];
    const float* semb = (const float*)d_in[3];
    const float* w1   = (const float*)d_in[4];
    const float* b1   = (const float*)d_in[5];
    const float* w2   = (const float*)d_in[6];
    const float* b2   = (const float*)d_in[7];
    float* out = (float*)d_out;

    // ---- workspace layout with liveness reuse (total ~311 MB) ----
    char* base = (char*)d_ws;
    unsigned short* Acat  = (unsigned short*)(base);               // [8192][3072] bf16 (hi|hi|lo)
    unsigned short* Bcat  = (unsigned short*)(base + 50331648);    // [4096][3072] bf16 (hi|lo|hi)
    unsigned short* dispT = (unsigned short*)(base);               // [2][4096][4096] (reuses Acat+Bcat)
    unsigned short* w2T   = (unsigned short*)(base);               // [8][1024][4096] (reuses dispT)
    float*          logits= (float*)(base + 75497472);             // [2][4096][4096] f32
    unsigned short* hbuf  = (unsigned short*)(base + 75497472);    // [16][512][4096] (reuses logits)
    unsigned short* w1T   = (unsigned short*)(base + 142606336);   // [8][4096][1024] (reuses logits+67MB)
    unsigned short* xnT   = (unsigned short*)(base + 209715200);   // [2][1024][4096]
    unsigned short* comb  = (unsigned short*)(base + 226492416);   // [2][4096][4096]
    unsigned short* slots = (unsigned short*)(base + 293601280);   // [2][4096][1024]
    unsigned short* eoT   = (unsigned short*)(base + 293601280);   // [2][1024][4096] (reuses slots)
    float* pmax = (float*)(base + 310378496);
    float* psum = pmax + 65536;
    float* cmax = psum + 65536;
    float* cinv = cmax + 8192;
    float* rmax = cinv + 8192;
    float* rinv = rmax + 8192;

    // 1. RMSNorm + hi/lo split
    rmsnorm_split<0><<<NB*SEQ, 256, 0, stream>>>(x, ng, Acat);
    rmsnorm_split<1><<<NEXP*NSLOT, 256, 0, stream>>>(semb, sg, Bcat);

    // 2. xnT[b][d][n] = hi(xn) transposed
    transpose_b16<<<dim3(DIM/32, SEQ/32, NB), 256, 0, stream>>>(
        Acat, xnT, 3072, SEQ, (long)SEQ*3072, (long)DIM*SEQ);

    // 3. logits = [x_hi|x_hi|x_lo] @ [s_hi|s_lo|s_hi]^T  (K=3072)
    mfma_gemm256<0,0><<<dim3(ES/256, (NB*SEQ)/256, 1), 512, 0, stream>>>(
        Acat, Bcat, logits, nullptr, ES, 3072, 3072, 3072, ES,
        0L, 0L, 0L, 1);

    // 4. softmax stats
    col_stats_partial<<<dim3(ES/256, 8, NB), 256, 0, stream>>>(logits, pmax, psum);
    col_stats_reduce<<<dim3(ES/256, NB), 256, 0, stream>>>(pmax, psum, cmax, cinv);
    row_stats<<<NB*SEQ, 256, 0, stream>>>(logits, rmax, rinv);

    // 5. comb + dispT (bf16). Acat/Bcat dead.
    make_weights<<<dim3(ES/32, SEQ/32, NB), 256, 0, stream>>>(
        logits, cmax, cinv, rmax, rinv, comb, dispT);

    // 6. w1T[e][hid][dim] (logits dead)
    transpose_f32_b16<<<dim3(HID/32, DIM/32, NEXP), 256, 0, stream>>>(
        w1, w1T, HID, DIM, (long)DIM*HID, (long)HID*DIM);

    // 7. slots = dispT @ xnT^T   M=4096 N=1024 K=4096
    mfma_gemmX<0,1><<<dim3(DIM/128, ES/256, NB), 512, 0, stream>>>(
        dispT, xnT, slots, nullptr, DIM, SEQ, SEQ, SEQ, DIM,
        (long)ES*SEQ, (long)DIM*SEQ, (long)ES*DIM, 0L, NB);

    // 8. w2T[e][dim][hid] (dispT dead)
    transpose_f32_b16<<<dim3(DIM/32, HID/32, NEXP), 256, 0, stream>>>(
        w2, w2T, DIM, HID, (long)HID*DIM, (long)DIM*HID);

    // 9. FF1: h = gelu(slots @ w1T^T + b1)  M=512 N=4096 K=1024
    mfma_gemm256<2,1><<<dim3(HID/256, NSLOT/256, NB*NEXP), 512, 0, stream>>>(
        slots, w1T, hbuf, b1, HID, DIM, DIM, DIM, HID,
        (long)NSLOT*DIM, (long)HID*DIM, (long)NSLOT*HID, NEXP);

    // 10. FF2: eoT = (h @ w2T^T + b2)^T  M=512 N=1024 K=4096
    mfma_gemmX<1,2><<<dim3(DIM/128, NSLOT/256, NB*NEXP), 512, 0, stream>>>(
        hbuf, w2T, eoT, b2, DIM, HID, HID, HID, ES,
        (long)NSLOT*HID, (long)DIM*HID, (long)(DIM*ES/NEXP), (long)(NSLOT - DIM*ES/NEXP), NEXP);

    // 11. out = comb @ eoT^T   M=4096 N=1024 K=4096
    mfma_gemmX<0,0><<<dim3(DIM/128, SEQ/256, NB), 512, 0, stream>>>(
        comb, eoT, out, nullptr, DIM, ES, ES, ES, DIM,
        (long)SEQ*ES, (long)DIM*ES, (long)SEQ*DIM, 0L, NB);
}

// Round 6
// 694.395 us; speedup vs baseline: 6.6211x; 1.0195x over previous
//
#include <hip/hip_runtime.h>
#include <math.h>

#define SEQ    4096
#define DIM    1024
#define NEXP   8
#define NSLOT  512
#define ES     4096
#define HID    4096
#define NB     2
#define RMS_SCALE 32.0f

typedef __attribute__((ext_vector_type(4))) float f32x4;
typedef __attribute__((ext_vector_type(8))) short bf16x8;
typedef __attribute__((ext_vector_type(4))) unsigned short us4;

__device__ __forceinline__ unsigned short f2bf(float f) {
    unsigned u = __float_as_uint(f);
    u += 0x7fff + ((u >> 16) & 1);          // round-to-nearest-even
    return (unsigned short)(u >> 16);
}
__device__ __forceinline__ float bf2f(unsigned short h) {
    return __uint_as_float(((unsigned)h) << 16);
}
__device__ __forceinline__ float gelu_exact(float x) {
    return 0.5f * x * (1.0f + erff(x * 0.70710678118654752f));
}

#define GLOAD_LDS16(gp, lp) \
    __builtin_amdgcn_global_load_lds((const __attribute__((address_space(1))) void*)(gp), \
                                     (__attribute__((address_space(3))) void*)(lp), 16, 0, 0)

__device__ __forceinline__ unsigned ldsoff(const void* p) {
    return (unsigned)(size_t)(const __attribute__((address_space(3))) void*)p;
}

#define DSR(dst, base, off) asm volatile("ds_read_b128 %0, %1 offset:" off : "=v"(dst) : "v"(base))
#define VM(n) asm volatile("s_waitcnt vmcnt(" #n ")" ::: "memory")
#define BAR __builtin_amdgcn_s_barrier()
#define SCB __builtin_amdgcn_sched_barrier(0)

#define PH_OPEN  SCB; BAR; asm volatile("s_waitcnt lgkmcnt(0)" ::: "memory"); SCB; \
                 __builtin_amdgcn_s_setprio(1);
#define PH_CLOSE __builtin_amdgcn_s_setprio(0); SCB;

// ---------------- RMSNorm + bf16 hi/lo split into K-concat layout ----------------
template<int ORDER>
__global__ void rmsnorm_split(const float* __restrict__ in, const float* __restrict__ gamma,
                              unsigned short* __restrict__ outc) {
    int row = blockIdx.x;
    int t = threadIdx.x;
    float4 v = reinterpret_cast<const float4*>(in + (size_t)row * DIM)[t];
    float ss = v.x*v.x + v.y*v.y + v.z*v.z + v.w*v.w;
    #pragma unroll
    for (int off = 32; off >= 1; off >>= 1) ss += __shfl_down(ss, off, 64);
    __shared__ float red[4];
    if ((t & 63) == 0) red[t >> 6] = ss;
    __syncthreads();
    float inv = RMS_SCALE / fmaxf(sqrtf(red[0] + red[1] + red[2] + red[3]), 1e-12f);
    float4 g = reinterpret_cast<const float4*>(gamma)[t];
    float f[4] = {v.x*inv*g.x, v.y*inv*g.y, v.z*inv*g.z, v.w*inv*g.w};
    us4 hv, lv;
    #pragma unroll
    for (int q = 0; q < 4; ++q) {
        unsigned short h = f2bf(f[q]);
        hv[q] = h;
        lv[q] = f2bf(f[q] - bf2f(h));
    }
    unsigned short* rb = outc + (size_t)row * 3072;
    *reinterpret_cast<us4*>(&rb[t*4]) = hv;
    if (ORDER == 0) {
        *reinterpret_cast<us4*>(&rb[1024 + t*4]) = hv;
        *reinterpret_cast<us4*>(&rb[2048 + t*4]) = lv;
    } else {
        *reinterpret_cast<us4*>(&rb[1024 + t*4]) = lv;
        *reinterpret_cast<us4*>(&rb[2048 + t*4]) = hv;
    }
}

// ---------------- partial-stats reduce kernels (consume GEMM-epilogue partials) -------
__global__ void row_reduce(const float* __restrict__ pM, const float* __restrict__ pS,
                           float* __restrict__ rmax, float* __restrict__ rinv) {
    int row = blockIdx.x * 256 + threadIdx.x;       // 0..8191 global row
    float m = -INFINITY, s = 0.f;
    for (int p = 0; p < 64; ++p) {
        float m2 = pM[(size_t)p*8192 + row], s2 = pS[(size_t)p*8192 + row];
        float mn = fmaxf(m, m2);
        s = s * __expf(m - mn) + s2 * __expf(m2 - mn);
        m = mn;
    }
    rmax[row] = m; rinv[row] = 1.0f / s;
}

__global__ void col_reduce(const float* __restrict__ pM, const float* __restrict__ pS,
                           float* __restrict__ cmax, float* __restrict__ cinv) {
    int col = blockIdx.x * 256 + threadIdx.x;       // 0..4095
    int b = blockIdx.y;
    float m = -INFINITY, s = 0.f;
    for (int p = b*32; p < b*32 + 32; ++p) {
        float m2 = pM[(size_t)p*4096 + col], s2 = pS[(size_t)p*4096 + col];
        float mn = fmaxf(m, m2);
        s = s * __expf(m - mn) + s2 * __expf(m2 - mn);
        m = mn;
    }
    cmax[b*4096 + col] = m; cinv[b*4096 + col] = 1.0f / s;
}

// ---------------- fused weights pass ----------------
__global__ void make_weights(const float* __restrict__ logits,
                             const float* __restrict__ cmax, const float* __restrict__ cinv,
                             const float* __restrict__ rmax, const float* __restrict__ rinv,
                             unsigned short* __restrict__ comb, unsigned short* __restrict__ dispT) {
    int b = blockIdx.z;
    const float* L = logits + (size_t)b * SEQ * ES;
    int n0 = blockIdx.y * 32, e0 = blockIdx.x * 32;
    int t = threadIdx.x;
    int r = t >> 3, c4 = (t & 7) * 4;
    __shared__ unsigned short tile[32][36];
    float4 v = *reinterpret_cast<const float4*>(&L[(size_t)(n0 + r) * ES + e0 + c4]);
    float rm = rmax[b*SEQ + n0 + r], ri = rinv[b*SEQ + n0 + r];
    float vv[4] = {v.x, v.y, v.z, v.w};
    us4 cb;
    #pragma unroll
    for (int q = 0; q < 4; ++q) {
        cb[q] = f2bf(__expf(vv[q] - rm) * ri);
        float dv = __expf(vv[q] - cmax[b*ES + e0 + c4 + q]) * cinv[b*ES + e0 + c4 + q];
        tile[c4 + q][r] = f2bf(dv);
    }
    *reinterpret_cast<us4*>(&comb[(size_t)b*SEQ*ES + (size_t)(n0 + r)*ES + e0 + c4]) = cb;
    __syncthreads();
    us4 o = *reinterpret_cast<us4*>(&tile[t >> 3][(t & 7) * 4]);
    *reinterpret_cast<us4*>(&dispT[(size_t)b*ES*SEQ + (size_t)(e0 + (t >> 3))*SEQ + n0 + (t & 7)*4]) = o;
}

// ---------------- bf16 -> bf16 transpose ----------------
__global__ void transpose_b16(const unsigned short* __restrict__ src, unsigned short* __restrict__ dst,
                              int sld, int dld, long sStride, long dStride) {
    int z = blockIdx.z;
    const unsigned short* S = src + (size_t)z * sStride;
    unsigned short* D = dst + (size_t)z * dStride;
    int r0 = blockIdx.y * 32, c0 = blockIdx.x * 32;
    int t = threadIdx.x;
    __shared__ unsigned short tile[32][36];
    us4 v = *reinterpret_cast<const us4*>(&S[(size_t)(r0 + (t>>3)) * sld + c0 + (t&7)*4]);
    #pragma unroll
    for (int q = 0; q < 4; ++q) tile[(t&7)*4 + q][t>>3] = v[q];
    __syncthreads();
    us4 o = *reinterpret_cast<us4*>(&tile[t >> 3][(t & 7) * 4]);
    *reinterpret_cast<us4*>(&D[(size_t)(c0 + (t>>3)) * dld + r0 + (t&7)*4]) = o;
}

// ---------------- f32 -> bf16 transpose ----------------
__global__ void transpose_f32_b16(const float* __restrict__ src, unsigned short* __restrict__ dst,
                                  int sld, int dld, long sStride, long dStride) {
    int z = blockIdx.z;
    const float* S = src + (size_t)z * sStride;
    unsigned short* D = dst + (size_t)z * dStride;
    int r0 = blockIdx.y * 32, c0 = blockIdx.x * 32;
    int t = threadIdx.x;
    __shared__ unsigned short tile[32][36];
    float4 v = *reinterpret_cast<const float4*>(&S[(size_t)(r0 + (t>>3)) * sld + c0 + (t&7)*4]);
    float vv[4] = {v.x, v.y, v.z, v.w};
    #pragma unroll
    for (int q = 0; q < 4; ++q) tile[(t&7)*4 + q][t>>3] = f2bf(vv[q]);
    __syncthreads();
    us4 o = *reinterpret_cast<us4*>(&tile[t >> 3][(t & 7) * 4]);
    *reinterpret_cast<us4*>(&D[(size_t)(c0 + (t>>3)) * dld + r0 + (t&7)*4]) = o;
}

// ================= 256x256 8-phase MFMA GEMM — quad halves, vmcnt(6)@P4/P8 =================
// Stage map (per iter tt, 2 K-tiles): s1@P1:Ah1(t+1)->b1, s2@P2:Ah0(t+2)->b0,
// s3@P3:Bh0(t+2)->b0, s4@P4:Bh1(t+2)->b0, s5@P5:Ah1(t+2)->b0, s6@P6:Ah0(t+3)->b1,
// s7@P7:Bh0(t+3)->b1, s8@P8:Bh1(t+3)->b1. Waits: vmcnt(6) at P4 (covers s8(tt-2),s1) and
// P8 (covers s5). Tail: last iter skips s2..s8, waits 0. STATS=1: fused softmax partials.
template<int EPI, int OM, int STATS>
__global__ __launch_bounds__(512, 2)
void mfma_gemm256(const unsigned short* __restrict__ A, const unsigned short* __restrict__ B,
                  void* __restrict__ Cv, const float* __restrict__ bias,
                  int N, int K, int lda, int ldb, int ldc,
                  long aStride, long bStride, long cStride, int bMod,
                  float* __restrict__ rowpM, float* __restrict__ rowpS,
                  float* __restrict__ colpM, float* __restrict__ colpS) {
    __shared__ unsigned short lds[65536];   // 128 KB
    const int t = threadIdx.x;
    const int lane = t & 63, wave = t >> 6;
    const int wr = wave >> 2, wc = wave & 3;
    const int z = blockIdx.z, zb = z % bMod;
    const unsigned short* Ab = A + (size_t)z * aStride;
    const unsigned short* Bb = B + (size_t)zb * bStride;
    const int gx = gridDim.x;
    int flat = blockIdx.x + blockIdx.y * gx;
    const int cpx = (gx * gridDim.y) >> 3;
    flat = (flat & 7) * cpx + (flat >> 3);
    const int m0 = (flat / gx) * 256, n0 = (flat % gx) * 256;

    const int sr = t >> 3;                    // slot-row within an 8KB load
    const int sg = (t & 7) ^ (sr & 7);        // pre-swizzled 16B group
    const unsigned short* gA = Ab + (size_t)(m0 + sr) * lda + sg * 8;
    const int srB = sr + (sr & 32);           // B quad row map
    const unsigned short* gB = Bb + (size_t)(n0 + srB) * ldb + sg * 8;
    unsigned short* ldsw = lds + wave * 512;

    const int lr = lane & 15, lk = lane >> 4;
    const unsigned sw0 = (unsigned)(((lk)     ^ (lr & 7)) << 4);
    const unsigned sw1 = (unsigned)(((4 + lk) ^ (lr & 7)) << 4);
    const unsigned l0  = ldsoff(lds);
    const unsigned arow = (unsigned)((wr*64 + lr) * 128);
    const unsigned brow = (unsigned)((wc*32 + lr) * 128);
    const unsigned ab00 = l0 + arow + sw0,          ab10 = l0 + arow + sw1;
    const unsigned bb00 = l0 + 32768 + brow + sw0,  bb10 = l0 + 32768 + brow + sw1;
    const unsigned ab01 = ab00 + 65536, ab11 = ab10 + 65536;
    const unsigned bb01 = bb00 + 65536, bb11 = bb10 + 65536;

    #define STAGE_A(buf, half, tt) do { \
        const unsigned short* _g = gA + (size_t)((half)*64) * lda + (tt)*64; \
        unsigned short* _l = ldsw + (buf)*32768 + (half)*8192; \
        GLOAD_LDS16(_g, _l); \
        GLOAD_LDS16(_g + (size_t)128*lda, _l + 4096); } while(0)
    #define STAGE_B(buf, half, tt) do { \
        const unsigned short* _g = gB + (size_t)((half)*32) * ldb + (tt)*64; \
        unsigned short* _l = ldsw + (buf)*32768 + 16384 + (half)*8192; \
        GLOAD_LDS16(_g, _l); \
        GLOAD_LDS16(_g + (size_t)128*ldb, _l + 4096); } while(0)

    #define MFMA16(MB, CN) \
        _Pragma("unroll") \
        for (int m = 0; m < 4; ++m) { \
            _Pragma("unroll") \
            for (int n = 0; n < 2; ++n) { \
                acc[(MB)+m][(CN)+n] = __builtin_amdgcn_mfma_f32_16x16x32_bf16(a0[m], b0[(CN)+n], acc[(MB)+m][(CN)+n], 0, 0, 0); \
                acc[(MB)+m][(CN)+n] = __builtin_amdgcn_mfma_f32_16x16x32_bf16(a1[m], b1[(CN)+n], acc[(MB)+m][(CN)+n], 0, 0, 0); \
            } \
        }

    f32x4 acc[8][4] = {};
    bf16x8 a0[4], a1[4], b0[4], b1[4];
    const int NT = K / 64;

    // prologue: tiles 0 (full) + 1 (Ah0,Bh0,Bh1); Ah1(1) comes from s1 of iter 0.
    STAGE_A(0, 0, 0); STAGE_B(0, 0, 0); STAGE_B(0, 1, 0); STAGE_A(0, 1, 0);
    STAGE_A(1, 0, 1); STAGE_B(1, 0, 1); STAGE_B(1, 1, 1);
    VM(0); BAR;

    for (int tt = 0; tt < NT; tt += 2) {
        const bool pf2 = (tt + 2 < NT);
        const bool pf3 = (tt + 3 < NT);
        // P1: read Ah0(t)+Bh0(t) [b0]; s1
        DSR(a0[0], ab00, "0");    DSR(a0[1], ab00, "2048");
        DSR(a0[2], ab00, "4096"); DSR(a0[3], ab00, "6144");
        DSR(a1[0], ab10, "0");    DSR(a1[1], ab10, "2048");
        DSR(a1[2], ab10, "4096"); DSR(a1[3], ab10, "6144");
        DSR(b0[0], bb00, "0");    DSR(b0[1], bb00, "2048");
        DSR(b1[0], bb10, "0");    DSR(b1[1], bb10, "2048");
        STAGE_A(1, 1, tt+1);
        PH_OPEN MFMA16(0, 0) PH_CLOSE
        BAR;
        // P2: read Bh1(t); s2
        DSR(b0[2], bb00, "16384"); DSR(b0[3], bb00, "18432");
        DSR(b1[2], bb10, "16384"); DSR(b1[3], bb10, "18432");
        if (pf2) STAGE_A(0, 0, tt+2);
        PH_OPEN MFMA16(0, 2) PH_CLOSE
        BAR;
        // P3: read Ah1(t); s3
        DSR(a0[0], ab00, "16384"); DSR(a0[1], ab00, "18432");
        DSR(a0[2], ab00, "20480"); DSR(a0[3], ab00, "22528");
        DSR(a1[0], ab10, "16384"); DSR(a1[1], ab10, "18432");
        DSR(a1[2], ab10, "20480"); DSR(a1[3], ab10, "22528");
        if (pf2) STAGE_B(0, 0, tt+2);
        PH_OPEN MFMA16(4, 0) PH_CLOSE
        BAR;
        // P4: s4; wait
        if (pf2) STAGE_B(0, 1, tt+2);
        PH_OPEN MFMA16(4, 2) PH_CLOSE
        if (pf2) { VM(6); } else { VM(0); }
        BAR;
        // P5: read Ah0(t+1)+Bh0(t+1) [b1]; s5
        DSR(a0[0], ab01, "0");    DSR(a0[1], ab01, "2048");
        DSR(a0[2], ab01, "4096"); DSR(a0[3], ab01, "6144");
        DSR(a1[0], ab11, "0");    DSR(a1[1], ab11, "2048");
        DSR(a1[2], ab11, "4096"); DSR(a1[3], ab11, "6144");
        DSR(b0[0], bb01, "0");    DSR(b0[1], bb01, "2048");
        DSR(b1[0], bb11, "0");    DSR(b1[1], bb11, "2048");
        if (pf2) STAGE_A(0, 1, tt+2);
        PH_OPEN MFMA16(0, 0) PH_CLOSE
        BAR;
        // P6: read Bh1(t+1); s6
        DSR(b0[2], bb01, "16384"); DSR(b0[3], bb01, "18432");
        DSR(b1[2], bb11, "16384"); DSR(b1[3], bb11, "18432");
        if (pf3) STAGE_A(1, 0, tt+3);
        PH_OPEN MFMA16(0, 2) PH_CLOSE
        BAR;
        // P7: read Ah1(t+1); s7
        DSR(a0[0], ab01, "16384"); DSR(a0[1], ab01, "18432");
        DSR(a0[2], ab01, "20480"); DSR(a0[3], ab01, "22528");
        DSR(a1[0], ab11, "16384"); DSR(a1[1], ab11, "18432");
        DSR(a1[2], ab11, "20480"); DSR(a1[3], ab11, "22528");
        if (pf3) STAGE_B(1, 0, tt+3);
        PH_OPEN MFMA16(4, 0) PH_CLOSE
        BAR;
        // P8: s8; wait
        if (pf3) STAGE_B(1, 1, tt+3);
        PH_OPEN MFMA16(4, 2) PH_CLOSE
        if (pf3) { VM(6); } else { VM(0); }
        BAR;
    }

    // ---- fused softmax stats partials (logits only) ----
    if (STATS) {
        // row partials: per row, max/sum over this wave's 64 cols
        #pragma unroll
        for (int f = 0; f < 8; ++f) {
            #pragma unroll
            for (int r = 0; r < 4; ++r) {
                float m = fmaxf(fmaxf(acc[f][0][r], acc[f][1][r]), fmaxf(acc[f][2][r], acc[f][3][r]));
                #pragma unroll
                for (int msk = 1; msk <= 8; msk <<= 1) m = fmaxf(m, __shfl_xor(m, msk, 64));
                float s = __expf(acc[f][0][r]-m) + __expf(acc[f][1][r]-m)
                        + __expf(acc[f][2][r]-m) + __expf(acc[f][3][r]-m);
                #pragma unroll
                for (int msk = 1; msk <= 8; msk <<= 1) s += __shfl_xor(s, msk, 64);
                if ((lane & 15) == 0) {
                    int row = m0 + wr*128 + f*16 + (lane>>4)*4 + r;
                    int slot = (n0 >> 6) + wc;       // xblk*4 + wc, 0..63
                    rowpM[(size_t)slot*8192 + row] = m;
                    rowpS[(size_t)slot*8192 + row] = s;
                }
            }
        }
        // col partials: per col, max/sum over this wave's 128 rows
        #pragma unroll
        for (int n = 0; n < 4; ++n) {
            float m = -INFINITY;
            #pragma unroll
            for (int f = 0; f < 8; ++f)
                #pragma unroll
                for (int r = 0; r < 4; ++r) m = fmaxf(m, acc[f][n][r]);
            m = fmaxf(m, __shfl_xor(m, 16, 64));
            m = fmaxf(m, __shfl_xor(m, 32, 64));
            float s = 0.f;
            #pragma unroll
            for (int f = 0; f < 8; ++f)
                #pragma unroll
                for (int r = 0; r < 4; ++r) s += __expf(acc[f][n][r] - m);
            s += __shfl_xor(s, 16, 64);
            s += __shfl_xor(s, 32, 64);
            if ((lane >> 4) == 0) {
                int col = n0 + wc*64 + n*16 + lane;
                int slot = (m0 >> 7) + wr;           // yblk*2 + wr, 0..63
                colpM[(size_t)slot*4096 + col] = m;
                colpS[(size_t)slot*4096 + col] = s;
            }
        }
    }

    const float* bz = (EPI != 0) ? bias + (size_t)zb * N : nullptr;
    long coff = (long)z * cStride;
    int rbase = (lane >> 4) * 4;
    int cbase = lane & 15;
    #pragma unroll
    for (int f = 0; f < 8; ++f) {
        #pragma unroll
        for (int n = 0; n < 4; ++n) {
            int col  = n0 + wc*64 + n*16 + cbase;
            int row0 = m0 + wr*128 + f*16 + rbase;
            float bv = (EPI != 0) ? bz[col] : 0.f;
            float vals[4];
            #pragma unroll
            for (int r = 0; r < 4; ++r) {
                float v = acc[f][n][r] + bv;
                if (EPI == 2) v = gelu_exact(v);
                vals[r] = v;
            }
            if (OM == 0) {
                float* C = (float*)Cv + coff;
                #pragma unroll
                for (int r = 0; r < 4; ++r) C[(size_t)(row0 + r) * ldc + col] = vals[r];
            } else {
                unsigned short* C = (unsigned short*)Cv + coff;
                #pragma unroll
                for (int r = 0; r < 4; ++r) C[(size_t)(row0 + r) * ldc + col] = f2bf(vals[r]);
            }
        }
    }
    #undef STAGE_A
    #undef STAGE_B
    #undef MFMA16
}

// ================= 256x128 8-phase MFMA GEMM — quad halves, vmcnt(4)@P4/P8 =================
// Stage map: s1@P1:Aq1(t+1)->b1, s2@P3:Aq0(t+2)->b0, s3@P4:B(t+2)->b0,
// s4@P5:Aq1(t+2)->b0, s5@P7:Aq0(t+3)->b1, s6@P8:B(t+3)->b1.
template<int EPI, int OM>
__global__ __launch_bounds__(512, 2)
void mfma_gemmX(const unsigned short* __restrict__ A, const unsigned short* __restrict__ B,
                void* __restrict__ Cv, const float* __restrict__ bias,
                int N, int K, int lda, int ldb, int ldc,
                long aStride, long bStride, long cStride, long cStrideE, int bMod) {
    __shared__ unsigned short lds[49152];   // 96 KB
    const int t = threadIdx.x;
    const int lane = t & 63, wave = t >> 6;
    const int wr = wave >> 2, wc = wave & 3;
    const int z = blockIdx.z, zb = z % bMod;
    const unsigned short* Ab = A + (size_t)z * aStride;
    const unsigned short* Bb = B + (size_t)zb * bStride;
    const int gx = gridDim.x;
    int flat = blockIdx.x + blockIdx.y * gx;
    const int cpx = (gx * gridDim.y) >> 3;
    flat = (flat & 7) * cpx + (flat >> 3);
    const int m0 = (flat / gx) * 256, n0 = (flat % gx) * 128;

    const int sr = t >> 3;
    const int sg = (t & 7) ^ (sr & 7);
    const unsigned short* gA = Ab + (size_t)(m0 + sr) * lda + sg * 8;
    const unsigned short* gB = Bb + (size_t)(n0 + sr) * ldb + sg * 8;
    unsigned short* ldsw = lds + wave * 512;

    const int lr = lane & 15, lk = lane >> 4;
    const unsigned g0 = (unsigned)(((lk)     ^ (lr & 7)) << 4);
    const unsigned g1 = (unsigned)(((4 + lk) ^ (lr & 7)) << 4);
    const unsigned l0 = ldsoff(lds);
    const unsigned arow = (unsigned)((wr*64 + lr) * 128);
    const unsigned brow = (unsigned)((wc*32 + lr) * 128);
    const unsigned ax00 = l0 + arow + g0,          ax10 = l0 + arow + g1;
    const unsigned bx00 = l0 + 32768 + brow + g0,  bx10 = l0 + 32768 + brow + g1;
    const unsigned ax01 = ax00 + 49152, ax11 = ax10 + 49152;
    const unsigned bx01 = bx00 + 49152, bx11 = bx10 + 49152;

    #define STAGE_AX(buf, quad, tt) do { \
        const unsigned short* _g = gA + (size_t)((quad)*64) * lda + (tt)*64; \
        unsigned short* _l = ldsw + (buf)*24576 + (quad)*8192; \
        GLOAD_LDS16(_g, _l); \
        GLOAD_LDS16(_g + (size_t)128*lda, _l + 4096); } while(0)
    #define STAGE_BX(buf, tt) do { \
        const unsigned short* _g = gB + (tt)*64; \
        unsigned short* _l = ldsw + (buf)*24576 + 16384; \
        GLOAD_LDS16(_g, _l); \
        GLOAD_LDS16(_g + (size_t)64*ldb, _l + 4096); } while(0)

    #define MFMA8(MB, AR, BR) \
        _Pragma("unroll") \
        for (int m = 0; m < 4; ++m) { \
            _Pragma("unroll") \
            for (int n = 0; n < 2; ++n) { \
                acc[(MB)+m][n] = __builtin_amdgcn_mfma_f32_16x16x32_bf16(AR[m], BR[n], acc[(MB)+m][n], 0, 0, 0); \
            } \
        }

    f32x4 acc[8][2] = {};
    bf16x8 a0[4], a1[4], b0[2], b1[2];
    const int NT = K / 64;

    // prologue: tile 0 full + tile 1 (Aq0, B); Aq1(1) from s1 of iter 0.
    STAGE_AX(0, 0, 0); STAGE_BX(0, 0); STAGE_AX(0, 1, 0);
    STAGE_AX(1, 0, 1); STAGE_BX(1, 1);
    VM(0); BAR;

    for (int tt = 0; tt < NT; tt += 2) {
        const bool pf2 = (tt + 2 < NT);
        const bool pf3 = (tt + 3 < NT);
        // P1: Aq0(t) kk0 + B(t) kk0 [b0]; s1
        DSR(a0[0], ax00, "0");    DSR(a0[1], ax00, "2048");
        DSR(a0[2], ax00, "4096"); DSR(a0[3], ax00, "6144");
        DSR(b0[0], bx00, "0");    DSR(b0[1], bx00, "2048");
        STAGE_AX(1, 1, tt+1);
        PH_OPEN MFMA8(0, a0, b0) PH_CLOSE
        BAR;
        // P2: kk1
        DSR(a1[0], ax10, "0");    DSR(a1[1], ax10, "2048");
        DSR(a1[2], ax10, "4096"); DSR(a1[3], ax10, "6144");
        DSR(b1[0], bx10, "0");    DSR(b1[1], bx10, "2048");
        PH_OPEN MFMA8(0, a1, b1) PH_CLOSE
        BAR;
        // P3: Aq1(t) kk0; s2
        DSR(a0[0], ax00, "16384"); DSR(a0[1], ax00, "18432");
        DSR(a0[2], ax00, "20480"); DSR(a0[3], ax00, "22528");
        if (pf2) STAGE_AX(0, 0, tt+2);
        PH_OPEN MFMA8(4, a0, b0) PH_CLOSE
        BAR;
        // P4: Aq1(t) kk1; s3; wait
        DSR(a1[0], ax10, "16384"); DSR(a1[1], ax10, "18432");
        DSR(a1[2], ax10, "20480"); DSR(a1[3], ax10, "22528");
        if (pf2) STAGE_BX(0, tt+2);
        PH_OPEN MFMA8(4, a1, b1) PH_CLOSE
        if (pf2) { VM(4); } else { VM(0); }
        BAR;
        // P5: Aq0(t+1) kk0 + B(t+1) kk0 [b1]; s4
        DSR(a0[0], ax01, "0");    DSR(a0[1], ax01, "2048");
        DSR(a0[2], ax01, "4096"); DSR(a0[3], ax01, "6144");
        DSR(b0[0], bx01, "0");    DSR(b0[1], bx01, "2048");
        if (pf2) STAGE_AX(0, 1, tt+2);
        PH_OPEN MFMA8(0, a0, b0) PH_CLOSE
        BAR;
        // P6: kk1
        DSR(a1[0], ax11, "0");    DSR(a1[1], ax11, "2048");
        DSR(a1[2], ax11, "4096"); DSR(a1[3], ax11, "6144");
        DSR(b1[0], bx11, "0");    DSR(b1[1], bx11, "2048");
        PH_OPEN MFMA8(0, a1, b1) PH_CLOSE
        BAR;
        // P7: Aq1(t+1) kk0; s5
        DSR(a0[0], ax01, "16384"); DSR(a0[1], ax01, "18432");
        DSR(a0[2], ax01, "20480"); DSR(a0[3], ax01, "22528");
        if (pf3) STAGE_AX(1, 0, tt+3);
        PH_OPEN MFMA8(4, a0, b0) PH_CLOSE
        BAR;
        // P8: Aq1(t+1) kk1; s6; wait
        DSR(a1[0], ax11, "16384"); DSR(a1[1], ax11, "18432");
        DSR(a1[2], ax11, "20480"); DSR(a1[3], ax11, "22528");
        if (pf3) STAGE_BX(1, tt+3);
        PH_OPEN MFMA8(4, a1, b1) PH_CLOSE
        if (pf3) { VM(4); } else { VM(0); }
        BAR;
    }

    const float* bz = (EPI != 0) ? bias + (size_t)zb * N : nullptr;
    long coff = (long)z * cStride + (long)zb * cStrideE;
    int rbase = (lane >> 4) * 4;
    int cbase = lane & 15;
    #pragma unroll
    for (int f = 0; f < 8; ++f) {
        #pragma unroll
        for (int n = 0; n < 2; ++n) {
            int col  = n0 + wc*32 + n*16 + cbase;
            int row0 = m0 + wr*128 + f*16 + rbase;
            float bv = (EPI != 0) ? bz[col] : 0.f;
            float vals[4];
            #pragma unroll
            for (int r = 0; r < 4; ++r) {
                float v = acc[f][n][r] + bv;
                if (EPI == 2) v = gelu_exact(v);
                vals[r] = v;
            }
            if (OM == 0) {
                float* C = (float*)Cv + coff;
                #pragma unroll
                for (int r = 0; r < 4; ++r) C[(size_t)(row0 + r) * ldc + col] = vals[r];
            } else if (OM == 1) {
                unsigned short* C = (unsigned short*)Cv + coff;
                #pragma unroll
                for (int r = 0; r < 4; ++r) C[(size_t)(row0 + r) * ldc + col] = f2bf(vals[r]);
            } else {
                unsigned short* C = (unsigned short*)Cv + coff;
                us4 o;
                #pragma unroll
                for (int r = 0; r < 4; ++r) o[r] = f2bf(vals[r]);
                *reinterpret_cast<us4*>(&C[(size_t)col * ldc + row0]) = o;
            }
        }
    }
    #undef STAGE_AX
    #undef STAGE_BX
    #undef MFMA8
}

extern "C" void kernel_launch(void* const* d_in, const int* in_sizes, int n_in,
                              void* d_out, int out_size, void* d_ws, size_t ws_size,
                              hipStream_t stream) {
    const float* x    = (const float*)d_in[0];
    const float* ng   = (const float*)d_in[1];
    const float* sg   = (const float*)d_in[2];
    const float* semb = (const float*)d_in[3];
    const float* w1   = (const float*)d_in[4];
    const float* b1   = (const float*)d_in[5];
    const float* w2   = (const float*)d_in[6];
    const float* b2   = (const float*)d_in[7];
    float* out = (float*)d_out;

    // ---- workspace layout with liveness reuse (total ~311 MB) ----
    char* base = (char*)d_ws;
    unsigned short* Acat  = (unsigned short*)(base);               // [8192][3072] bf16 (hi|hi|lo)
    unsigned short* Bcat  = (unsigned short*)(base + 50331648);    // [4096][3072] bf16 (hi|lo|hi)
    unsigned short* dispT = (unsigned short*)(base);               // [2][4096][4096] (reuses Acat+Bcat)
    unsigned short* w2T   = (unsigned short*)(base);               // [8][1024][4096] (reuses dispT)
    float*          logits= (float*)(base + 75497472);             // [2][4096][4096] f32
    unsigned short* hbuf  = (unsigned short*)(base + 75497472);    // [16][512][4096] (reuses logits)
    unsigned short* w1T   = (unsigned short*)(base + 142606336);   // [8][4096][1024] (reuses logits+67MB)
    unsigned short* xnT   = (unsigned short*)(base + 209715200);   // [2][1024][4096]
    unsigned short* comb  = (unsigned short*)(base + 226492416);   // [2][4096][4096]
    unsigned short* slots = (unsigned short*)(base + 293601280);   // [2][4096][1024]
    unsigned short* eoT   = (unsigned short*)(base + 293601280);   // [2][1024][4096] (reuses slots)
    // stats partials live in the comb region (dead until make_weights)
    float* rowpM = (float*)(base + 226492416);        // [64][8192]
    float* rowpS = rowpM + 64*8192;                   // [64][8192]
    float* colpM = rowpS + 64*8192;                   // [64][4096]
    float* colpS = colpM + 64*4096;                   // [64][4096]
    float* cmax = (float*)(base + 310378496);
    float* cinv = cmax + 8192;
    float* rmax = cinv + 8192;
    float* rinv = rmax + 8192;

    // 1. RMSNorm + hi/lo split
    rmsnorm_split<0><<<NB*SEQ, 256, 0, stream>>>(x, ng, Acat);
    rmsnorm_split<1><<<NEXP*NSLOT, 256, 0, stream>>>(semb, sg, Bcat);

    // 2. xnT[b][d][n] = hi(xn) transposed
    transpose_b16<<<dim3(DIM/32, SEQ/32, NB), 256, 0, stream>>>(
        Acat, xnT, 3072, SEQ, (long)SEQ*3072, (long)DIM*SEQ);

    // 3. logits (K=3072) + fused softmax stat partials
    mfma_gemm256<0,0,1><<<dim3(ES/256, (NB*SEQ)/256, 1), 512, 0, stream>>>(
        Acat, Bcat, logits, nullptr, ES, 3072, 3072, 3072, ES,
        0L, 0L, 0L, 1, rowpM, rowpS, colpM, colpS);

    // 4. partial-stat reduction
    row_reduce<<<32, 256, 0, stream>>>(rowpM, rowpS, rmax, rinv);
    col_reduce<<<dim3(16, 2), 256, 0, stream>>>(colpM, colpS, cmax, cinv);

    // 5. comb + dispT (bf16). Acat/Bcat dead; partials dead after step 4.
    make_weights<<<dim3(ES/32, SEQ/32, NB), 256, 0, stream>>>(
        logits, cmax, cinv, rmax, rinv, comb, dispT);

    // 6. w1T[e][hid][dim] (logits dead)
    transpose_f32_b16<<<dim3(HID/32, DIM/32, NEXP), 256, 0, stream>>>(
        w1, w1T, HID, DIM, (long)DIM*HID, (long)HID*DIM);

    // 7. slots = dispT @ xnT^T   M=4096 N=1024 K=4096
    mfma_gemmX<0,1><<<dim3(DIM/128, ES/256, NB), 512, 0, stream>>>(
        dispT, xnT, slots, nullptr, DIM, SEQ, SEQ, SEQ, DIM,
        (long)ES*SEQ, (long)DIM*SEQ, (long)ES*DIM, 0L, NB);

    // 8. w2T[e][dim][hid] (dispT dead)
    transpose_f32_b16<<<dim3(DIM/32, HID/32, NEXP), 256, 0, stream>>>(
        w2, w2T, DIM, HID, (long)HID*DIM, (long)DIM*HID);

    // 9. FF1: h = gelu(slots @ w1T^T + b1)  M=512 N=4096 K=1024
    mfma_gemm256<2,1,0><<<dim3(HID/256, NSLOT/256, NB*NEXP), 512, 0, stream>>>(
        slots, w1T, hbuf, b1, HID, DIM, DIM, DIM, HID,
        (long)NSLOT*DIM, (long)HID*DIM, (long)NSLOT*HID, NEXP,
        nullptr, nullptr, nullptr, nullptr);

    // 10. FF2: eoT = (h @ w2T^T + b2)^T  M=512 N=1024 K=4096
    mfma_gemmX<1,2><<<dim3(DIM/128, NSLOT/256, NB*NEXP), 512, 0, stream>>>(
        hbuf, w2T, eoT, b2, DIM, HID, HID, HID, ES,
        (long)NSLOT*HID, (long)DIM*HID, (long)(DIM*ES/NEXP), (long)(NSLOT - DIM*ES/NEXP), NEXP);

    // 11. out = comb @ eoT^T   M=4096 N=1024 K=4096
    mfma_gemmX<0,0><<<dim3(DIM/128, SEQ/256, NB), 512, 0, stream>>>(
        comb, eoT, out, nullptr, DIM, ES, ES, ES, DIM,
        (long)SEQ*ES, (long)DIM*ES, (long)SEQ*DIM, 0L, NB);
}